// Round 13
// baseline (489.215 us; speedup 1.0000x reference)
//
#include <hip/hip_runtime.h>
#include <hip/hip_bf16.h>
#include <math.h>

#define N_NODESC 100000
#define N_EDGESC 1600000
#define N_GRAPHSC 128
#define IN_DIMC 64
#define HIDC 128
#define OUT_DIMC 16
#define NUM_ITERSC 4
#define GAMMAC 0.1f
#define EPSC 0.1f
#define POOL_CHUNKS 8
#define UPD_NB ((N_NODESC + 63) / 64)

// bucketed CSR build
#define NBUK 98                         // ceil(100000/1024), bucket = dst>>10
#define EPB 4096                        // edges per hist/scatter block
#define NBLK ((N_EDGESC + EPB - 1) / EPB)   // 391
#define NHIST (NBUK * NBLK)             // 38318
#define S1NB ((NHIST + 255) / 256)      // 150

typedef __attribute__((ext_vector_type(8))) short bf16x8;
typedef __attribute__((ext_vector_type(4))) float f32x4;
typedef __attribute__((ext_vector_type(2))) float f32x2;

__device__ __forceinline__ unsigned short f2bf(float f) {
  unsigned int u = __float_as_uint(f);
  unsigned int r = (u + 0x7fffu + ((u >> 16) & 1u)) >> 16;  // RNE
  return (unsigned short)r;
}

__device__ __forceinline__ unsigned char f2q(float f) {  // f32 -> OCP e4m3 (HW RNE)
  unsigned int p = (unsigned int)__builtin_amdgcn_cvt_pk_fp8_f32(f, 0.f, 0, false);
  return (unsigned char)(p & 0xFFu);
}

__device__ __forceinline__ float tanh_fast(float x) {
  float a = fminf(fabsf(x), 15.0f);
  float e = __expf(2.0f * a);
  float r = (e - 1.0f) * __builtin_amdgcn_rcpf(e + 1.0f);
  return copysignf(r, x);
}

// Fused weight pack: MTP (update weights, 32768 elems) + EWP (embed weights, 8192 elems)
__global__ __launch_bounds__(256) void k_pack(const float* __restrict__ W,
                                              const float* __restrict__ lin_w,
                                              const float* __restrict__ emb_w,
                                              unsigned short* __restrict__ MTP,
                                              unsigned short* __restrict__ EWP) {
  int idx = blockIdx.x * 256 + threadIdx.x;
  if (idx < 32768) {
    int j = idx & 7;
    int lane = (idx >> 3) & 63;
    int t = idx >> 9;  // ct*8+kc
    int kc = t & 7, ct = t >> 3;
    int k = kc * 32 + (lane >> 4) * 8 + j;
    int c = ct * 16 + (lane & 15);
    float v;
    if (k < HIDC) v = W[c * HIDC + k] - W[k * HIDC + c] - ((k == c) ? GAMMAC : 0.0f);
    else v = lin_w[c * HIDC + (k - HIDC)];
    MTP[idx] = f2bf(v);
  } else if (idx < 32768 + 8192) {
    int i2 = idx - 32768;
    int j = i2 & 7;
    int lane = (i2 >> 3) & 63;
    int t = i2 >> 9;  // ct*2+kc
    int kc = t & 1, ct = t >> 1;
    int k = kc * 32 + (lane >> 4) * 8 + j;
    int c = ct * 16 + (lane & 15);
    EWP[i2] = f2bf(emb_w[c * IN_DIMC + k]);
  }
}

// hb = bf16(x @ emb_w.T + emb_b) via MFMA; also writes fp8 gather shadow hq
__global__ __launch_bounds__(256) void k_embed_mfma(const float* __restrict__ x,
                                                    const unsigned short* __restrict__ EWP,
                                                    const float* __restrict__ emb_b,
                                                    unsigned short* __restrict__ hb,
                                                    unsigned char* __restrict__ hq) {
  __shared__ __align__(16) unsigned char Xls[64 * 128];  // 64 rows x 64 bf16, swizzled
  int tid = threadIdx.x;
  int r0 = blockIdx.x * 64;
  for (int i = tid; i < 512; i += 256) {
    int row = i >> 3, ck = i & 7;
    int gr = r0 + row;
    uint4 v = make_uint4(0u, 0u, 0u, 0u);
    if (gr < N_NODESC) {
      const float* xp = x + (size_t)gr * IN_DIMC + ck * 8;
      float4 f0 = *(const float4*)xp;
      float4 f1 = *(const float4*)(xp + 4);
      v.x = (unsigned)f2bf(f0.x) | ((unsigned)f2bf(f0.y) << 16);
      v.y = (unsigned)f2bf(f0.z) | ((unsigned)f2bf(f0.w) << 16);
      v.z = (unsigned)f2bf(f1.x) | ((unsigned)f2bf(f1.y) << 16);
      v.w = (unsigned)f2bf(f1.z) | ((unsigned)f2bf(f1.w) << 16);
    }
    *(uint4*)(Xls + row * 128 + ((ck * 16) ^ ((row & 7) << 4))) = v;
  }
  __syncthreads();
  int lane = tid & 63, w = tid >> 6;
  int m = lane & 15, g = lane >> 4;
  int arow = w * 16 + m;
  bf16x8 a0 = *(const bf16x8*)(Xls + arow * 128 + ((g * 16) ^ ((arow & 7) << 4)));
  bf16x8 a1 = *(const bf16x8*)(Xls + arow * 128 + ((64 + g * 16) ^ ((arow & 7) << 4)));
  f32x4 acc[8];
#pragma unroll
  for (int ct = 0; ct < 8; ++ct) acc[ct] = (f32x4){0.f, 0.f, 0.f, 0.f};
#pragma unroll
  for (int ct = 0; ct < 8; ++ct) {
    bf16x8 b0 = *(const bf16x8*)(EWP + ((size_t)((ct * 2 + 0) * 64 + lane)) * 8);
    bf16x8 b1 = *(const bf16x8*)(EWP + ((size_t)((ct * 2 + 1) * 64 + lane)) * 8);
    acc[ct] = __builtin_amdgcn_mfma_f32_16x16x32_bf16(a0, b0, acc[ct], 0, 0, 0);
    acc[ct] = __builtin_amdgcn_mfma_f32_16x16x32_bf16(a1, b1, acc[ct], 0, 0, 0);
  }
#pragma unroll
  for (int ct = 0; ct < 8; ++ct) {
    int col = ct * 16 + m;
    float bias = emb_b[col];
#pragma unroll
    for (int j = 0; j < 4; ++j) {
      int grow = r0 + w * 16 + g * 4 + j;
      if (grow < N_NODESC) {
        float val = acc[ct][j] + bias;
        hb[(size_t)grow * HIDC + col] = f2bf(val);
        hq[(size_t)grow * HIDC + col] = f2q(val);
      }
    }
  }
}

// ---- bucketed CSR build ----
__global__ __launch_bounds__(256) void k_hist(const int* __restrict__ dst, int* __restrict__ histg) {
  __shared__ int hl[NBUK];
  int tid = threadIdx.x;
  for (int i = tid; i < NBUK; i += 256) hl[i] = 0;
  __syncthreads();
  int base = blockIdx.x * EPB;
  int end = base + EPB;
  if (end > N_EDGESC) end = N_EDGESC;
  for (int e = base + tid; e < end; e += 256) atomicAdd(&hl[dst[e] >> 10], 1);
  __syncthreads();
  for (int i = tid; i < NBUK; i += 256) histg[i * NBLK + blockIdx.x] = hl[i];
}

__global__ __launch_bounds__(256) void k_s1(const int* __restrict__ in, int* __restrict__ bsum) {
  __shared__ int red[256];
  int tid = threadIdx.x;
  int i = blockIdx.x * 256 + tid;
  red[tid] = (i < NHIST) ? in[i] : 0;
  __syncthreads();
#pragma unroll
  for (int off = 128; off > 0; off >>= 1) {
    if (tid < off) red[tid] += red[tid + off];
    __syncthreads();
  }
  if (tid == 0) bsum[blockIdx.x] = red[0];
}

__global__ __launch_bounds__(256) void k_s2(int* __restrict__ bsum, int* __restrict__ boff) {
  __shared__ int buf[256];
  int tid = threadIdx.x;
  int v = (tid < S1NB) ? bsum[tid] : 0;
  buf[tid] = v;
  __syncthreads();
  for (int off = 1; off < 256; off <<= 1) {
    int t = (tid >= off) ? buf[tid - off] : 0;
    __syncthreads();
    buf[tid] += t;
    __syncthreads();
  }
  if (tid < S1NB) boff[tid] = buf[tid] - v;
}

__global__ __launch_bounds__(256) void k_s3(const int* __restrict__ in, const int* __restrict__ boff,
                                            int* __restrict__ out) {
  __shared__ int buf[256];
  int tid = threadIdx.x;
  int i = blockIdx.x * 256 + tid;
  int v = (i < NHIST) ? in[i] : 0;
  buf[tid] = v;
  __syncthreads();
  for (int off = 1; off < 256; off <<= 1) {
    int t = (tid >= off) ? buf[tid - off] : 0;
    __syncthreads();
    buf[tid] += t;
    __syncthreads();
  }
  if (i < NHIST) out[i] = boff[blockIdx.x] + buf[tid] - v;
}

__global__ __launch_bounds__(256) void k_scatter(const int* __restrict__ src, const int* __restrict__ dst,
                                                 const int* __restrict__ hoff, unsigned int* __restrict__ ebuf) {
  __shared__ int cur[NBUK];
  int tid = threadIdx.x;
  for (int i = tid; i < NBUK; i += 256) cur[i] = hoff[i * NBLK + blockIdx.x];
  __syncthreads();
  int base = blockIdx.x * EPB;
  int end = base + EPB;
  if (end > N_EDGESC) end = N_EDGESC;
  for (int e = base + tid; e < end; e += 256) {
    int d = dst[e];
    int bu = d >> 10;
    int pos = atomicAdd(&cur[bu], 1);
    ebuf[pos] = ((unsigned int)(d & 1023) << 17) | (unsigned int)src[e];
  }
}

// colidx stores BYTE OFFSETS into hq (src * 128) for address-free gather loads
__global__ __launch_bounds__(256) void k_csr(const unsigned int* __restrict__ ebuf,
                                             const int* __restrict__ hoff,
                                             int* __restrict__ rowptr, int* __restrict__ colidx) {
  __shared__ int lcnt[1024];
  __shared__ int lcur[1024];
  __shared__ int ssum[256];
  int b = blockIdx.x, tid = threadIdx.x;
  int ebeg = hoff[b * NBLK];
  int eend = (b + 1 < NBUK) ? hoff[(b + 1) * NBLK] : N_EDGESC;
  for (int i = tid; i < 1024; i += 256) lcnt[i] = 0;
  __syncthreads();
  for (int e = ebeg + tid; e < eend; e += 256) atomicAdd(&lcnt[ebuf[e] >> 17], 1);
  __syncthreads();
  int c0 = lcnt[tid * 4 + 0], c1 = lcnt[tid * 4 + 1], c2 = lcnt[tid * 4 + 2], c3 = lcnt[tid * 4 + 3];
  int s = c0 + c1 + c2 + c3;
  ssum[tid] = s;
  __syncthreads();
  for (int off = 1; off < 256; off <<= 1) {
    int t = (tid >= off) ? ssum[tid - off] : 0;
    __syncthreads();
    ssum[tid] += t;
    __syncthreads();
  }
  int excl = ssum[tid] - s;
  int node0 = (b << 10) + tid * 4;
  int ex = excl;
  lcur[tid * 4 + 0] = ex; if (node0 + 0 < N_NODESC) rowptr[node0 + 0] = ebeg + ex; ex += c0;
  lcur[tid * 4 + 1] = ex; if (node0 + 1 < N_NODESC) rowptr[node0 + 1] = ebeg + ex; ex += c1;
  lcur[tid * 4 + 2] = ex; if (node0 + 2 < N_NODESC) rowptr[node0 + 2] = ebeg + ex; ex += c2;
  lcur[tid * 4 + 3] = ex; if (node0 + 3 < N_NODESC) rowptr[node0 + 3] = ebeg + ex;
  __syncthreads();
  for (int e = ebeg + tid; e < eend; e += 256) {
    unsigned int u = ebuf[e];
    int pos = atomicAdd(&lcur[u >> 17], 1);
    colidx[ebeg + pos] = (int)((u & 0x1FFFFu) << 7);  // byte offset: src * HIDC
  }
  if (b == 0 && tid == 0) rowptr[N_NODESC] = N_EDGESC;
}

// agg over in-edges from fp8 shadow; one wave per node.
// lane = (edge slot g 0..7) x (16-col chunk l 0..7); uint4 = 16B fp8 per lane.
// One wave-load covers 8 rows (2048B in flight); main loop 16 edges/iter, 2 loads deep.
__global__ __launch_bounds__(256) void k_gather_q(const unsigned char* __restrict__ hq,
                                                  const int* __restrict__ rowptr,
                                                  const int* __restrict__ colidx,
                                                  unsigned short* __restrict__ aggb) {
  int node = blockIdx.x * 4 + (threadIdx.x >> 6);
  int lane = threadIdx.x & 63;
  if (node >= N_NODESC) return;
  int g = lane >> 3;   // edge slot 0..7
  int l = lane & 7;    // 16B chunk 0..7 (cols 16l..16l+15)
  int beg = rowptr[node], end = rowptr[node + 1];
  f32x2 acc2[8];
#pragma unroll
  for (int i = 0; i < 8; ++i) acc2[i] = (f32x2){0.f, 0.f};
  int e = beg;
  for (; e + 16 <= end; e += 16) {
    int o0 = colidx[e + g];
    int o1 = colidx[e + 8 + g];
    uint4 u0 = ((const uint4*)(hq + (size_t)(unsigned)o0))[l];
    uint4 u1 = ((const uint4*)(hq + (size_t)(unsigned)o1))[l];
    acc2[0] += __builtin_amdgcn_cvt_pk_f32_fp8((int)u0.x, false);
    acc2[1] += __builtin_amdgcn_cvt_pk_f32_fp8((int)u0.x, true);
    acc2[2] += __builtin_amdgcn_cvt_pk_f32_fp8((int)u0.y, false);
    acc2[3] += __builtin_amdgcn_cvt_pk_f32_fp8((int)u0.y, true);
    acc2[4] += __builtin_amdgcn_cvt_pk_f32_fp8((int)u0.z, false);
    acc2[5] += __builtin_amdgcn_cvt_pk_f32_fp8((int)u0.z, true);
    acc2[6] += __builtin_amdgcn_cvt_pk_f32_fp8((int)u0.w, false);
    acc2[7] += __builtin_amdgcn_cvt_pk_f32_fp8((int)u0.w, true);
    acc2[0] += __builtin_amdgcn_cvt_pk_f32_fp8((int)u1.x, false);
    acc2[1] += __builtin_amdgcn_cvt_pk_f32_fp8((int)u1.x, true);
    acc2[2] += __builtin_amdgcn_cvt_pk_f32_fp8((int)u1.y, false);
    acc2[3] += __builtin_amdgcn_cvt_pk_f32_fp8((int)u1.y, true);
    acc2[4] += __builtin_amdgcn_cvt_pk_f32_fp8((int)u1.z, false);
    acc2[5] += __builtin_amdgcn_cvt_pk_f32_fp8((int)u1.z, true);
    acc2[6] += __builtin_amdgcn_cvt_pk_f32_fp8((int)u1.w, false);
    acc2[7] += __builtin_amdgcn_cvt_pk_f32_fp8((int)u1.w, true);
  }
  if (e + 8 <= end) {
    int o0 = colidx[e + g];
    uint4 u0 = ((const uint4*)(hq + (size_t)(unsigned)o0))[l];
    acc2[0] += __builtin_amdgcn_cvt_pk_f32_fp8((int)u0.x, false);
    acc2[1] += __builtin_amdgcn_cvt_pk_f32_fp8((int)u0.x, true);
    acc2[2] += __builtin_amdgcn_cvt_pk_f32_fp8((int)u0.y, false);
    acc2[3] += __builtin_amdgcn_cvt_pk_f32_fp8((int)u0.y, true);
    acc2[4] += __builtin_amdgcn_cvt_pk_f32_fp8((int)u0.z, false);
    acc2[5] += __builtin_amdgcn_cvt_pk_f32_fp8((int)u0.z, true);
    acc2[6] += __builtin_amdgcn_cvt_pk_f32_fp8((int)u0.w, false);
    acc2[7] += __builtin_amdgcn_cvt_pk_f32_fp8((int)u0.w, true);
    e += 8;
  }
  // tail (up to 7 edges): one predicated slot covers e+g, g=0..7
  {
    int eg = e + g;
    if (eg < end) {
      int o0 = colidx[eg];
      uint4 u0 = ((const uint4*)(hq + (size_t)(unsigned)o0))[l];
      acc2[0] += __builtin_amdgcn_cvt_pk_f32_fp8((int)u0.x, false);
      acc2[1] += __builtin_amdgcn_cvt_pk_f32_fp8((int)u0.x, true);
      acc2[2] += __builtin_amdgcn_cvt_pk_f32_fp8((int)u0.y, false);
      acc2[3] += __builtin_amdgcn_cvt_pk_f32_fp8((int)u0.y, true);
      acc2[4] += __builtin_amdgcn_cvt_pk_f32_fp8((int)u0.z, false);
      acc2[5] += __builtin_amdgcn_cvt_pk_f32_fp8((int)u0.z, true);
      acc2[6] += __builtin_amdgcn_cvt_pk_f32_fp8((int)u0.w, false);
      acc2[7] += __builtin_amdgcn_cvt_pk_f32_fp8((int)u0.w, true);
    }
  }
  // reduce across the 8 edge slots (lane stride 8)
#pragma unroll
  for (int i = 0; i < 8; ++i) {
    acc2[i].x += __shfl_xor(acc2[i].x, 8);
    acc2[i].y += __shfl_xor(acc2[i].y, 8);
    acc2[i].x += __shfl_xor(acc2[i].x, 16);
    acc2[i].y += __shfl_xor(acc2[i].y, 16);
    acc2[i].x += __shfl_xor(acc2[i].x, 32);
    acc2[i].y += __shfl_xor(acc2[i].y, 32);
  }
  if (g == 0) {
    uint4 o0, o1;
    o0.x = (unsigned)f2bf(acc2[0].x) | ((unsigned)f2bf(acc2[0].y) << 16);
    o0.y = (unsigned)f2bf(acc2[1].x) | ((unsigned)f2bf(acc2[1].y) << 16);
    o0.z = (unsigned)f2bf(acc2[2].x) | ((unsigned)f2bf(acc2[2].y) << 16);
    o0.w = (unsigned)f2bf(acc2[3].x) | ((unsigned)f2bf(acc2[3].y) << 16);
    o1.x = (unsigned)f2bf(acc2[4].x) | ((unsigned)f2bf(acc2[4].y) << 16);
    o1.y = (unsigned)f2bf(acc2[5].x) | ((unsigned)f2bf(acc2[5].y) << 16);
    o1.z = (unsigned)f2bf(acc2[6].x) | ((unsigned)f2bf(acc2[6].y) << 16);
    o1.w = (unsigned)f2bf(acc2[7].x) | ((unsigned)f2bf(acc2[7].y) << 16);
    ((uint4*)(aggb + (size_t)node * HIDC))[2 * l] = o0;
    ((uint4*)(aggb + (size_t)node * HIDC))[2 * l + 1] = o1;
  }
}

// conv = [hb|aggb] @ M^T via MFMA bf16 (K=256); hb = bf16(hb + eps*tanh(conv+b)) in place;
// refresh fp8 shadow hq. Epilogue: results restaged into the (dead) agg-half of LDS
// (wave-private rows, no barrier), then fully-vectorized uint4/uint2 copy-out.
__global__ __launch_bounds__(256) void k_update_mfma(unsigned short* __restrict__ hb,
                                                     unsigned char* __restrict__ hq,
                                                     const unsigned short* __restrict__ aggb,
                                                     const unsigned short* __restrict__ MTP,
                                                     const float* __restrict__ asym_b) {
  __shared__ __align__(16) unsigned char Als[64 * 512];
  int tid = threadIdx.x;
  int r0 = blockIdx.x * 64;
  for (int i = tid; i < 2048; i += 256) {
    int row = i >> 5;
    int ck = i & 31;
    int gr = r0 + row;
    uint4 v = make_uint4(0u, 0u, 0u, 0u);
    if (gr < N_NODESC) {
      if (ck < 16) v = ((const uint4*)(hb + (size_t)gr * HIDC))[ck];
      else v = ((const uint4*)(aggb + (size_t)gr * HIDC))[ck - 16];
    }
    *(uint4*)(Als + row * 512 + ((ck * 16) ^ ((row & 7) << 4))) = v;
  }
  __syncthreads();
  int lane = tid & 63, w = tid >> 6;
  int m = lane & 15, g = lane >> 4;
  int arow = w * 16 + m;
  bf16x8 a[8];
#pragma unroll
  for (int kc = 0; kc < 8; ++kc) {
    a[kc] = *(const bf16x8*)(Als + arow * 512 + ((kc * 64 + g * 16) ^ ((arow & 7) << 4)));
  }
  f32x4 acc[8];
#pragma unroll
  for (int ct = 0; ct < 8; ++ct) acc[ct] = (f32x4){0.f, 0.f, 0.f, 0.f};
#pragma unroll
  for (int ct = 0; ct < 8; ++ct) {
#pragma unroll
    for (int kc = 0; kc < 8; ++kc) {
      bf16x8 b = *(const bf16x8*)(MTP + ((size_t)((ct * 8 + kc) * 64 + lane)) * 8);
      acc[ct] = __builtin_amdgcn_mfma_f32_16x16x32_bf16(a[kc], b, acc[ct], 0, 0, 0);
    }
  }
  // epilogue: val -> bf16 into agg-half of LDS (own-wave rows only; same swizzle +256)
#pragma unroll
  for (int ct = 0; ct < 8; ++ct) {
    int col = ct * 16 + m;
    float bias = asym_b[col];
    int lb = col * 2;  // byte offset of col within a row's half
#pragma unroll
    for (int j = 0; j < 4; ++j) {
      int lrow = w * 16 + g * 4 + j;
      int haddr = lrow * 512 + (((lb & ~15) ^ ((lrow & 7) << 4)) | (lb & 15));
      unsigned short hu = *(const unsigned short*)(Als + haddr);
      float hold = __uint_as_float((unsigned)hu << 16);
      float val = hold + EPSC * tanh_fast(acc[ct][j] + bias);
      *(unsigned short*)(Als + haddr + 256) = f2bf(val);
    }
  }
  // copy-out: wave w copies its 16 rows; uint4 hb stores + uint2 hq stores, coalesced
#pragma unroll
  for (int k = 0; k < 4; ++k) {
    int idx = k * 64 + lane;           // 0..255 per wave
    int row = w * 16 + (idx >> 4);
    int ck = idx & 15;                 // 16B chunk in out half
    int gr = r0 + row;
    if (gr < N_NODESC) {
      uint4 v = *(const uint4*)(Als + row * 512 + 256 + ((ck * 16) ^ ((row & 7) << 4)));
      ((uint4*)(hb + (size_t)gr * HIDC))[ck] = v;
      float f0 = __uint_as_float(v.x << 16), f1 = __uint_as_float(v.x & 0xffff0000u);
      float f2 = __uint_as_float(v.y << 16), f3 = __uint_as_float(v.y & 0xffff0000u);
      float f4 = __uint_as_float(v.z << 16), f5 = __uint_as_float(v.z & 0xffff0000u);
      float f6 = __uint_as_float(v.w << 16), f7 = __uint_as_float(v.w & 0xffff0000u);
      unsigned int w0 = 0u, w1 = 0u;
      w0 = (unsigned int)__builtin_amdgcn_cvt_pk_fp8_f32(f0, f1, (int)w0, false);
      w0 = (unsigned int)__builtin_amdgcn_cvt_pk_fp8_f32(f2, f3, (int)w0, true);
      w1 = (unsigned int)__builtin_amdgcn_cvt_pk_fp8_f32(f4, f5, (int)w1, false);
      w1 = (unsigned int)__builtin_amdgcn_cvt_pk_fp8_f32(f6, f7, (int)w1, true);
      uint2 q;
      q.x = w0;
      q.y = w1;
      ((uint2*)(hq + (size_t)gr * HIDC))[ck] = q;
    }
  }
}

__device__ __forceinline__ int lbound_batch(const int* __restrict__ a, int key) {
  int lo = 0, hi = N_NODESC;
  while (lo < hi) {
    int mid = (lo + hi) >> 1;
    if (a[mid] < key) lo = mid + 1;
    else hi = mid;
  }
  return lo;
}

__global__ __launch_bounds__(128) void k_pool1(const unsigned short* __restrict__ hb,
                                               const int* __restrict__ batch,
                                               float* __restrict__ part) {
  int g = blockIdx.x / POOL_CHUNKS;
  int j = blockIdx.x % POOL_CHUNKS;
  int c = threadIdx.x;
  int lo = lbound_batch(batch, g);
  int hi = lbound_batch(batch, g + 1);
  int n = hi - lo;
  int ch = (n + POOL_CHUNKS - 1) / POOL_CHUNKS;
  int b = lo + j * ch;
  int e = b + ch;
  if (e > hi) e = hi;
  float s = 0.f, m = -INFINITY;
  for (int i = b; i < e; ++i) {
    unsigned short u = hb[(size_t)i * HIDC + c];
    float v = __uint_as_float((unsigned)u << 16);
    s += v;
    m = fmaxf(m, v);
  }
  size_t o = ((size_t)g * POOL_CHUNKS + j) * 256;
  part[o + c] = s;
  part[o + 128 + c] = m;
}

// fused: combine pool partials -> [add|max|mean] -> mlp1 -> mlp2 -> out. one block per graph.
__global__ __launch_bounds__(192) void k_tail(const float* __restrict__ part,
                                              const int* __restrict__ batch,
                                              const float* __restrict__ r1_w,
                                              const float* __restrict__ r1_b,
                                              const float* __restrict__ r2_w,
                                              const float* __restrict__ r2_b,
                                              float* __restrict__ out) {
  __shared__ float gv[384];
  __shared__ float g1[192];
  int g = blockIdx.x;
  int tid = threadIdx.x;
  if (tid < 128) {
    int c = tid;
    float s = 0.f, m = -INFINITY;
#pragma unroll
    for (int j = 0; j < POOL_CHUNKS; ++j) {
      size_t o = ((size_t)g * POOL_CHUNKS + j) * 256;
      s += part[o + c];
      m = fmaxf(m, part[o + 128 + c]);
    }
    int lo = lbound_batch(batch, g);
    int hi = lbound_batch(batch, g + 1);
    float cntf = (float)(hi - lo);
    gv[c] = s;
    gv[128 + c] = m;
    gv[256 + c] = s / fmaxf(cntf, 1.f);
  }
  __syncthreads();
  {
    int j = tid;
    float acc = r1_b[j];
    const float* wr = r1_w + (size_t)j * 384;
#pragma unroll 4
    for (int k = 0; k < 384; ++k) acc = fmaf(gv[k], wr[k], acc);
    g1[j] = (acc > 0.f) ? acc : 0.01f * acc;
  }
  __syncthreads();
  if (tid < OUT_DIMC) {
    int o = tid;
    float acc = r2_b[o];
    const float* wr = r2_w + o * 192;
    for (int k = 0; k < 192; ++k) acc = fmaf(g1[k], wr[k], acc);
    out[g * OUT_DIMC + o] = (acc > 0.f) ? acc : 0.01f * acc;
  }
}

extern "C" void kernel_launch(void* const* d_in, const int* in_sizes, int n_in,
                              void* d_out, int out_size, void* d_ws, size_t ws_size,
                              hipStream_t stream) {
  const float* x      = (const float*)d_in[0];
  const int*   ei     = (const int*)d_in[1];
  const int*   batch  = (const int*)d_in[2];
  const float* emb_w  = (const float*)d_in[3];
  const float* emb_b  = (const float*)d_in[4];
  const float* W      = (const float*)d_in[5];
  const float* asym_b = (const float*)d_in[6];
  const float* lin_w  = (const float*)d_in[7];
  const float* r1_w   = (const float*)d_in[8];
  const float* r1_b   = (const float*)d_in[9];
  const float* r2_w   = (const float*)d_in[10];
  const float* r2_b   = (const float*)d_in[11];
  float* out = (float*)d_out;

  char* ws = (char*)d_ws;
  size_t off = 0;
  auto alloc = [&](size_t bytes) -> char* {
    char* p = ws + off;
    off += (bytes + 255) & ~(size_t)255;
    return p;
  };
  unsigned short* hb  = (unsigned short*)alloc((size_t)N_NODESC * HIDC * 2);  // 25.6 MB
  unsigned char*  hq  = (unsigned char*)alloc((size_t)N_NODESC * HIDC);       // 12.8 MB
  unsigned short* ab  = (unsigned short*)alloc((size_t)N_NODESC * HIDC * 2);  // 25.6 MB
  unsigned short* MTP = (unsigned short*)alloc((size_t)32768 * 2);            // 64 KB
  unsigned short* EWP = (unsigned short*)alloc((size_t)8192 * 2);             // 16 KB
  int* rowptr   = (int*)alloc((size_t)(N_NODESC + 1) * 4);
  int* colidx   = (int*)alloc((size_t)N_EDGESC * 4);                // 6.4 MB
  unsigned int* ebuf = (unsigned int*)alloc((size_t)N_EDGESC * 4);  // 6.4 MB
  int* histg    = (int*)alloc((size_t)NHIST * 4);
  int* hoff     = (int*)alloc((size_t)NHIST * 4);
  int* bsum     = (int*)alloc((size_t)S1NB * 4);
  int* boff     = (int*)alloc((size_t)S1NB * 4);
  float* part   = (float*)alloc((size_t)N_GRAPHSC * POOL_CHUNKS * 256 * 4);
  (void)ws_size; (void)in_sizes; (void)n_in; (void)out_size;

  const int* srcv = ei;
  const int* dstv = ei + N_EDGESC;

  k_pack<<<(32768 + 8192 + 255) / 256, 256, 0, stream>>>(W, lin_w, emb_w, MTP, EWP);
  k_embed_mfma<<<UPD_NB, 256, 0, stream>>>(x, EWP, emb_b, hb, hq);
  k_hist<<<NBLK, 256, 0, stream>>>(dstv, histg);
  k_s1<<<S1NB, 256, 0, stream>>>(histg, bsum);
  k_s2<<<1, 256, 0, stream>>>(bsum, boff);
  k_s3<<<S1NB, 256, 0, stream>>>(histg, boff, hoff);
  k_scatter<<<NBLK, 256, 0, stream>>>(srcv, dstv, hoff, ebuf);
  k_csr<<<NBUK, 256, 0, stream>>>(ebuf, hoff, rowptr, colidx);
  for (int it = 0; it < NUM_ITERSC; ++it) {
    k_gather_q<<<N_NODESC / 4, 256, 0, stream>>>(hq, rowptr, colidx, ab);
    k_update_mfma<<<UPD_NB, 256, 0, stream>>>(hb, hq, ab, MTP, asym_b);
  }
  k_pool1<<<N_GRAPHSC * POOL_CHUNKS, 128, 0, stream>>>(hb, batch, part);
  k_tail<<<N_GRAPHSC, 192, 0, stream>>>(part, batch, r1_w, r1_b, r2_w, r2_b, out);
}

// Round 15
// 430.005 us; speedup vs baseline: 1.1377x; 1.1377x over previous
//
#include <hip/hip_runtime.h>
#include <hip/hip_bf16.h>
#include <math.h>

#define N_NODESC 100000
#define N_EDGESC 1600000
#define N_GRAPHSC 128
#define IN_DIMC 64
#define HIDC 128
#define OUT_DIMC 16
#define NUM_ITERSC 4
#define GAMMAC 0.1f
#define EPSC 0.1f
#define POOL_CHUNKS 8
#define UPD_NB ((N_NODESC + 63) / 64)

// bucketed CSR build
#define NBUK 98                         // ceil(100000/1024), bucket = dst>>10
#define EPB 4096                        // edges per hist/scatter block
#define NBLK ((N_EDGESC + EPB - 1) / EPB)   // 391
#define NHIST (NBUK * NBLK)             // 38318
#define S1NB ((NHIST + 255) / 256)      // 150

typedef __attribute__((ext_vector_type(8))) short bf16x8;
typedef __attribute__((ext_vector_type(4))) float f32x4;
typedef __attribute__((ext_vector_type(2))) float f32x2;

__device__ __forceinline__ unsigned short f2bf(float f) {
  unsigned int u = __float_as_uint(f);
  unsigned int r = (u + 0x7fffu + ((u >> 16) & 1u)) >> 16;  // RNE
  return (unsigned short)r;
}

__device__ __forceinline__ unsigned char f2q(float f) {  // f32 -> OCP e4m3 (HW RNE)
  unsigned int p = (unsigned int)__builtin_amdgcn_cvt_pk_fp8_f32(f, 0.f, 0, false);
  return (unsigned char)(p & 0xFFu);
}

__device__ __forceinline__ float tanh_fast(float x) {
  float a = fminf(fabsf(x), 15.0f);
  float e = __expf(2.0f * a);
  float r = (e - 1.0f) * __builtin_amdgcn_rcpf(e + 1.0f);
  return copysignf(r, x);
}

// Fused weight pack: MTP (update weights, 32768 elems) + EWP (embed weights, 8192 elems)
__global__ __launch_bounds__(256) void k_pack(const float* __restrict__ W,
                                              const float* __restrict__ lin_w,
                                              const float* __restrict__ emb_w,
                                              unsigned short* __restrict__ MTP,
                                              unsigned short* __restrict__ EWP) {
  int idx = blockIdx.x * 256 + threadIdx.x;
  if (idx < 32768) {
    int j = idx & 7;
    int lane = (idx >> 3) & 63;
    int t = idx >> 9;  // ct*8+kc
    int kc = t & 7, ct = t >> 3;
    int k = kc * 32 + (lane >> 4) * 8 + j;
    int c = ct * 16 + (lane & 15);
    float v;
    if (k < HIDC) v = W[c * HIDC + k] - W[k * HIDC + c] - ((k == c) ? GAMMAC : 0.0f);
    else v = lin_w[c * HIDC + (k - HIDC)];
    MTP[idx] = f2bf(v);
  } else if (idx < 32768 + 8192) {
    int i2 = idx - 32768;
    int j = i2 & 7;
    int lane = (i2 >> 3) & 63;
    int t = i2 >> 9;  // ct*2+kc
    int kc = t & 1, ct = t >> 1;
    int k = kc * 32 + (lane >> 4) * 8 + j;
    int c = ct * 16 + (lane & 15);
    EWP[i2] = f2bf(emb_w[c * IN_DIMC + k]);
  }
}

// hb = bf16(x @ emb_w.T + emb_b) via MFMA; also writes fp8 gather shadow hq
__global__ __launch_bounds__(256) void k_embed_mfma(const float* __restrict__ x,
                                                    const unsigned short* __restrict__ EWP,
                                                    const float* __restrict__ emb_b,
                                                    unsigned short* __restrict__ hb,
                                                    unsigned char* __restrict__ hq) {
  __shared__ __align__(16) unsigned char Xls[64 * 128];  // 64 rows x 64 bf16, swizzled
  int tid = threadIdx.x;
  int r0 = blockIdx.x * 64;
  for (int i = tid; i < 512; i += 256) {
    int row = i >> 3, ck = i & 7;
    int gr = r0 + row;
    uint4 v = make_uint4(0u, 0u, 0u, 0u);
    if (gr < N_NODESC) {
      const float* xp = x + (size_t)gr * IN_DIMC + ck * 8;
      float4 f0 = *(const float4*)xp;
      float4 f1 = *(const float4*)(xp + 4);
      v.x = (unsigned)f2bf(f0.x) | ((unsigned)f2bf(f0.y) << 16);
      v.y = (unsigned)f2bf(f0.z) | ((unsigned)f2bf(f0.w) << 16);
      v.z = (unsigned)f2bf(f1.x) | ((unsigned)f2bf(f1.y) << 16);
      v.w = (unsigned)f2bf(f1.z) | ((unsigned)f2bf(f1.w) << 16);
    }
    *(uint4*)(Xls + row * 128 + ((ck * 16) ^ ((row & 7) << 4))) = v;
  }
  __syncthreads();
  int lane = tid & 63, w = tid >> 6;
  int m = lane & 15, g = lane >> 4;
  int arow = w * 16 + m;
  bf16x8 a0 = *(const bf16x8*)(Xls + arow * 128 + ((g * 16) ^ ((arow & 7) << 4)));
  bf16x8 a1 = *(const bf16x8*)(Xls + arow * 128 + ((64 + g * 16) ^ ((arow & 7) << 4)));
  f32x4 acc[8];
#pragma unroll
  for (int ct = 0; ct < 8; ++ct) acc[ct] = (f32x4){0.f, 0.f, 0.f, 0.f};
#pragma unroll
  for (int ct = 0; ct < 8; ++ct) {
    bf16x8 b0 = *(const bf16x8*)(EWP + ((size_t)((ct * 2 + 0) * 64 + lane)) * 8);
    bf16x8 b1 = *(const bf16x8*)(EWP + ((size_t)((ct * 2 + 1) * 64 + lane)) * 8);
    acc[ct] = __builtin_amdgcn_mfma_f32_16x16x32_bf16(a0, b0, acc[ct], 0, 0, 0);
    acc[ct] = __builtin_amdgcn_mfma_f32_16x16x32_bf16(a1, b1, acc[ct], 0, 0, 0);
  }
#pragma unroll
  for (int ct = 0; ct < 8; ++ct) {
    int col = ct * 16 + m;
    float bias = emb_b[col];
#pragma unroll
    for (int j = 0; j < 4; ++j) {
      int grow = r0 + w * 16 + g * 4 + j;
      if (grow < N_NODESC) {
        float val = acc[ct][j] + bias;
        hb[(size_t)grow * HIDC + col] = f2bf(val);
        hq[(size_t)grow * HIDC + col] = f2q(val);
      }
    }
  }
}

// ---- bucketed CSR build ----
__global__ __launch_bounds__(256) void k_hist(const int* __restrict__ dst, int* __restrict__ histg) {
  __shared__ int hl[NBUK];
  int tid = threadIdx.x;
  for (int i = tid; i < NBUK; i += 256) hl[i] = 0;
  __syncthreads();
  int base = blockIdx.x * EPB;
  int end = base + EPB;
  if (end > N_EDGESC) end = N_EDGESC;
  for (int e = base + tid; e < end; e += 256) atomicAdd(&hl[dst[e] >> 10], 1);
  __syncthreads();
  for (int i = tid; i < NBUK; i += 256) histg[i * NBLK + blockIdx.x] = hl[i];
}

__global__ __launch_bounds__(256) void k_s1(const int* __restrict__ in, int* __restrict__ bsum) {
  __shared__ int red[256];
  int tid = threadIdx.x;
  int i = blockIdx.x * 256 + tid;
  red[tid] = (i < NHIST) ? in[i] : 0;
  __syncthreads();
#pragma unroll
  for (int off = 128; off > 0; off >>= 1) {
    if (tid < off) red[tid] += red[tid + off];
    __syncthreads();
  }
  if (tid == 0) bsum[blockIdx.x] = red[0];
}

__global__ __launch_bounds__(256) void k_s2(int* __restrict__ bsum, int* __restrict__ boff) {
  __shared__ int buf[256];
  int tid = threadIdx.x;
  int v = (tid < S1NB) ? bsum[tid] : 0;
  buf[tid] = v;
  __syncthreads();
  for (int off = 1; off < 256; off <<= 1) {
    int t = (tid >= off) ? buf[tid - off] : 0;
    __syncthreads();
    buf[tid] += t;
    __syncthreads();
  }
  if (tid < S1NB) boff[tid] = buf[tid] - v;
}

__global__ __launch_bounds__(256) void k_s3(const int* __restrict__ in, const int* __restrict__ boff,
                                            int* __restrict__ out) {
  __shared__ int buf[256];
  int tid = threadIdx.x;
  int i = blockIdx.x * 256 + tid;
  int v = (i < NHIST) ? in[i] : 0;
  buf[tid] = v;
  __syncthreads();
  for (int off = 1; off < 256; off <<= 1) {
    int t = (tid >= off) ? buf[tid - off] : 0;
    __syncthreads();
    buf[tid] += t;
    __syncthreads();
  }
  if (i < NHIST) out[i] = boff[blockIdx.x] + buf[tid] - v;
}

__global__ __launch_bounds__(256) void k_scatter(const int* __restrict__ src, const int* __restrict__ dst,
                                                 const int* __restrict__ hoff, unsigned int* __restrict__ ebuf) {
  __shared__ int cur[NBUK];
  int tid = threadIdx.x;
  for (int i = tid; i < NBUK; i += 256) cur[i] = hoff[i * NBLK + blockIdx.x];
  __syncthreads();
  int base = blockIdx.x * EPB;
  int end = base + EPB;
  if (end > N_EDGESC) end = N_EDGESC;
  for (int e = base + tid; e < end; e += 256) {
    int d = dst[e];
    int bu = d >> 10;
    int pos = atomicAdd(&cur[bu], 1);
    ebuf[pos] = ((unsigned int)(d & 1023) << 17) | (unsigned int)src[e];
  }
}

// colidx stores BYTE OFFSETS into hq (src * 128) for address-free gather loads
__global__ __launch_bounds__(256) void k_csr(const unsigned int* __restrict__ ebuf,
                                             const int* __restrict__ hoff,
                                             int* __restrict__ rowptr, int* __restrict__ colidx) {
  __shared__ int lcnt[1024];
  __shared__ int lcur[1024];
  __shared__ int ssum[256];
  int b = blockIdx.x, tid = threadIdx.x;
  int ebeg = hoff[b * NBLK];
  int eend = (b + 1 < NBUK) ? hoff[(b + 1) * NBLK] : N_EDGESC;
  for (int i = tid; i < 1024; i += 256) lcnt[i] = 0;
  __syncthreads();
  for (int e = ebeg + tid; e < eend; e += 256) atomicAdd(&lcnt[ebuf[e] >> 17], 1);
  __syncthreads();
  int c0 = lcnt[tid * 4 + 0], c1 = lcnt[tid * 4 + 1], c2 = lcnt[tid * 4 + 2], c3 = lcnt[tid * 4 + 3];
  int s = c0 + c1 + c2 + c3;
  ssum[tid] = s;
  __syncthreads();
  for (int off = 1; off < 256; off <<= 1) {
    int t = (tid >= off) ? ssum[tid - off] : 0;
    __syncthreads();
    ssum[tid] += t;
    __syncthreads();
  }
  int excl = ssum[tid] - s;
  int node0 = (b << 10) + tid * 4;
  int ex = excl;
  lcur[tid * 4 + 0] = ex; if (node0 + 0 < N_NODESC) rowptr[node0 + 0] = ebeg + ex; ex += c0;
  lcur[tid * 4 + 1] = ex; if (node0 + 1 < N_NODESC) rowptr[node0 + 1] = ebeg + ex; ex += c1;
  lcur[tid * 4 + 2] = ex; if (node0 + 2 < N_NODESC) rowptr[node0 + 2] = ebeg + ex; ex += c2;
  lcur[tid * 4 + 3] = ex; if (node0 + 3 < N_NODESC) rowptr[node0 + 3] = ebeg + ex;
  __syncthreads();
  for (int e = ebeg + tid; e < eend; e += 256) {
    unsigned int u = ebuf[e];
    int pos = atomicAdd(&lcur[u >> 17], 1);
    colidx[ebeg + pos] = (int)((u & 0x1FFFFu) << 7);  // byte offset: src * HIDC
  }
  if (b == 0 && tid == 0) rowptr[N_NODESC] = N_EDGESC;
}

// agg over in-edges from fp8 shadow; one wave per node.
// lane = (edge slot g 0..3) x (8-col chunk l 0..15); uint2 = 8B fp8 per lane.
// colidx preloaded per <=64-edge window, broadcast via __shfl.
// NOTE: every __shfl is executed wave-uniformly (outside per-lane branches) —
// ds_bpermute from an exec-masked lane returns garbage (R13 bug).
__global__ __launch_bounds__(256) void k_gather_q(const unsigned char* __restrict__ hq,
                                                  const int* __restrict__ rowptr,
                                                  const int* __restrict__ colidx,
                                                  unsigned short* __restrict__ aggb) {
  int node = blockIdx.x * 4 + (threadIdx.x >> 6);
  int lane = threadIdx.x & 63;
  if (node >= N_NODESC) return;
  int g = lane >> 4;   // edge slot 0..3
  int l = lane & 15;   // 8B chunk 0..15
  int beg = rowptr[node], end = rowptr[node + 1];
  f32x2 acc2[4];
#pragma unroll
  for (int i = 0; i < 4; ++i) acc2[i] = (f32x2){0.f, 0.f};
  int wbase = beg;
  int cv = (wbase + lane < end) ? colidx[wbase + lane] : 0;
  int e = beg;
  for (; e + 16 <= end; e += 16) {   // all conditions wave-uniform
    if (e + 16 > wbase + 64) {
      wbase = e;
      cv = (wbase + lane < end) ? colidx[wbase + lane] : 0;
    }
    int i0 = e - wbase;
    int o0 = __shfl(cv, i0 + g);
    int o1 = __shfl(cv, i0 + 4 + g);
    int o2 = __shfl(cv, i0 + 8 + g);
    int o3 = __shfl(cv, i0 + 12 + g);
    uint2 u0 = ((const uint2*)(hq + (size_t)(unsigned)o0))[l];
    uint2 u1 = ((const uint2*)(hq + (size_t)(unsigned)o1))[l];
    uint2 u2 = ((const uint2*)(hq + (size_t)(unsigned)o2))[l];
    uint2 u3 = ((const uint2*)(hq + (size_t)(unsigned)o3))[l];
    acc2[0] += __builtin_amdgcn_cvt_pk_f32_fp8((int)u0.x, false);
    acc2[1] += __builtin_amdgcn_cvt_pk_f32_fp8((int)u0.x, true);
    acc2[2] += __builtin_amdgcn_cvt_pk_f32_fp8((int)u0.y, false);
    acc2[3] += __builtin_amdgcn_cvt_pk_f32_fp8((int)u0.y, true);
    acc2[0] += __builtin_amdgcn_cvt_pk_f32_fp8((int)u1.x, false);
    acc2[1] += __builtin_amdgcn_cvt_pk_f32_fp8((int)u1.x, true);
    acc2[2] += __builtin_amdgcn_cvt_pk_f32_fp8((int)u1.y, false);
    acc2[3] += __builtin_amdgcn_cvt_pk_f32_fp8((int)u1.y, true);
    acc2[0] += __builtin_amdgcn_cvt_pk_f32_fp8((int)u2.x, false);
    acc2[1] += __builtin_amdgcn_cvt_pk_f32_fp8((int)u2.x, true);
    acc2[2] += __builtin_amdgcn_cvt_pk_f32_fp8((int)u2.y, false);
    acc2[3] += __builtin_amdgcn_cvt_pk_f32_fp8((int)u2.y, true);
    acc2[0] += __builtin_amdgcn_cvt_pk_f32_fp8((int)u3.x, false);
    acc2[1] += __builtin_amdgcn_cvt_pk_f32_fp8((int)u3.x, true);
    acc2[2] += __builtin_amdgcn_cvt_pk_f32_fp8((int)u3.y, false);
    acc2[3] += __builtin_amdgcn_cvt_pk_f32_fp8((int)u3.y, true);
  }
  if (e + 8 <= end) {                // wave-uniform
    if (e + 8 > wbase + 64) {
      wbase = e;
      cv = (wbase + lane < end) ? colidx[wbase + lane] : 0;
    }
    int i0 = e - wbase;
    int o0 = __shfl(cv, i0 + g);
    int o1 = __shfl(cv, i0 + 4 + g);
    uint2 u0 = ((const uint2*)(hq + (size_t)(unsigned)o0))[l];
    uint2 u1 = ((const uint2*)(hq + (size_t)(unsigned)o1))[l];
    acc2[0] += __builtin_amdgcn_cvt_pk_f32_fp8((int)u0.x, false);
    acc2[1] += __builtin_amdgcn_cvt_pk_f32_fp8((int)u0.x, true);
    acc2[2] += __builtin_amdgcn_cvt_pk_f32_fp8((int)u0.y, false);
    acc2[3] += __builtin_amdgcn_cvt_pk_f32_fp8((int)u0.y, true);
    acc2[0] += __builtin_amdgcn_cvt_pk_f32_fp8((int)u1.x, false);
    acc2[1] += __builtin_amdgcn_cvt_pk_f32_fp8((int)u1.x, true);
    acc2[2] += __builtin_amdgcn_cvt_pk_f32_fp8((int)u1.y, false);
    acc2[3] += __builtin_amdgcn_cvt_pk_f32_fp8((int)u1.y, true);
    e += 8;
  }
  // tail (up to 7 edges): shfl hoisted OUT of the divergent guard (R13 fix)
  if (e < end) {                     // wave-uniform
    if (e + 8 > wbase + 64) {
      wbase = e;
      cv = (wbase + lane < end) ? colidx[wbase + lane] : 0;
    }
#pragma unroll
    for (int t = 0; t < 2; ++t) {
      int eg = e + t * 4 + g;
      int o0 = __shfl(cv, (eg - wbase) & 63);  // executed by ALL lanes
      if (eg < end) {                          // divergence only on load+acc
        uint2 u0 = ((const uint2*)(hq + (size_t)(unsigned)o0))[l];
        acc2[0] += __builtin_amdgcn_cvt_pk_f32_fp8((int)u0.x, false);
        acc2[1] += __builtin_amdgcn_cvt_pk_f32_fp8((int)u0.x, true);
        acc2[2] += __builtin_amdgcn_cvt_pk_f32_fp8((int)u0.y, false);
        acc2[3] += __builtin_amdgcn_cvt_pk_f32_fp8((int)u0.y, true);
      }
    }
  }
  // reduce across the 4 edge slots
#pragma unroll
  for (int i = 0; i < 4; ++i) {
    acc2[i].x += __shfl_xor(acc2[i].x, 16);
    acc2[i].y += __shfl_xor(acc2[i].y, 16);
    acc2[i].x += __shfl_xor(acc2[i].x, 32);
    acc2[i].y += __shfl_xor(acc2[i].y, 32);
  }
  if (g == 0) {
    uint4 o;
    o.x = (unsigned)f2bf(acc2[0].x) | ((unsigned)f2bf(acc2[0].y) << 16);
    o.y = (unsigned)f2bf(acc2[1].x) | ((unsigned)f2bf(acc2[1].y) << 16);
    o.z = (unsigned)f2bf(acc2[2].x) | ((unsigned)f2bf(acc2[2].y) << 16);
    o.w = (unsigned)f2bf(acc2[3].x) | ((unsigned)f2bf(acc2[3].y) << 16);
    ((uint4*)(aggb + (size_t)node * HIDC))[l] = o;
  }
}

// conv = [hb|aggb] @ M^T via MFMA bf16 (K=256); hb = bf16(hb + eps*tanh(conv+b)) in place;
// refresh fp8 shadow hq. Epilogue: results restaged into the (dead) agg-half of LDS
// (wave-private rows, no barrier), then fully-vectorized uint4/uint2 copy-out.
__global__ __launch_bounds__(256) void k_update_mfma(unsigned short* __restrict__ hb,
                                                     unsigned char* __restrict__ hq,
                                                     const unsigned short* __restrict__ aggb,
                                                     const unsigned short* __restrict__ MTP,
                                                     const float* __restrict__ asym_b) {
  __shared__ __align__(16) unsigned char Als[64 * 512];
  int tid = threadIdx.x;
  int r0 = blockIdx.x * 64;
  for (int i = tid; i < 2048; i += 256) {
    int row = i >> 5;
    int ck = i & 31;
    int gr = r0 + row;
    uint4 v = make_uint4(0u, 0u, 0u, 0u);
    if (gr < N_NODESC) {
      if (ck < 16) v = ((const uint4*)(hb + (size_t)gr * HIDC))[ck];
      else v = ((const uint4*)(aggb + (size_t)gr * HIDC))[ck - 16];
    }
    *(uint4*)(Als + row * 512 + ((ck * 16) ^ ((row & 7) << 4))) = v;
  }
  __syncthreads();
  int lane = tid & 63, w = tid >> 6;
  int m = lane & 15, g = lane >> 4;
  int arow = w * 16 + m;
  bf16x8 a[8];
#pragma unroll
  for (int kc = 0; kc < 8; ++kc) {
    a[kc] = *(const bf16x8*)(Als + arow * 512 + ((kc * 64 + g * 16) ^ ((arow & 7) << 4)));
  }
  f32x4 acc[8];
#pragma unroll
  for (int ct = 0; ct < 8; ++ct) acc[ct] = (f32x4){0.f, 0.f, 0.f, 0.f};
#pragma unroll
  for (int ct = 0; ct < 8; ++ct) {
#pragma unroll
    for (int kc = 0; kc < 8; ++kc) {
      bf16x8 b = *(const bf16x8*)(MTP + ((size_t)((ct * 8 + kc) * 64 + lane)) * 8);
      acc[ct] = __builtin_amdgcn_mfma_f32_16x16x32_bf16(a[kc], b, acc[ct], 0, 0, 0);
    }
  }
  // epilogue: val -> bf16 into agg-half of LDS (own-wave rows only; same swizzle +256)
#pragma unroll
  for (int ct = 0; ct < 8; ++ct) {
    int col = ct * 16 + m;
    float bias = asym_b[col];
    int lb = col * 2;  // byte offset of col within a row's half
#pragma unroll
    for (int j = 0; j < 4; ++j) {
      int lrow = w * 16 + g * 4 + j;
      int haddr = lrow * 512 + (((lb & ~15) ^ ((lrow & 7) << 4)) | (lb & 15));
      unsigned short hu = *(const unsigned short*)(Als + haddr);
      float hold = __uint_as_float((unsigned)hu << 16);
      float val = hold + EPSC * tanh_fast(acc[ct][j] + bias);
      *(unsigned short*)(Als + haddr + 256) = f2bf(val);
    }
  }
  // copy-out: wave w copies its 16 rows; uint4 hb stores + uint2 hq stores, coalesced
#pragma unroll
  for (int k = 0; k < 4; ++k) {
    int idx = k * 64 + lane;           // 0..255 per wave
    int row = w * 16 + (idx >> 4);
    int ck = idx & 15;                 // 16B chunk in out half
    int gr = r0 + row;
    if (gr < N_NODESC) {
      uint4 v = *(const uint4*)(Als + row * 512 + 256 + ((ck * 16) ^ ((row & 7) << 4)));
      ((uint4*)(hb + (size_t)gr * HIDC))[ck] = v;
      float f0 = __uint_as_float(v.x << 16), f1 = __uint_as_float(v.x & 0xffff0000u);
      float f2 = __uint_as_float(v.y << 16), f3 = __uint_as_float(v.y & 0xffff0000u);
      float f4 = __uint_as_float(v.z << 16), f5 = __uint_as_float(v.z & 0xffff0000u);
      float f6 = __uint_as_float(v.w << 16), f7 = __uint_as_float(v.w & 0xffff0000u);
      unsigned int w0 = 0u, w1 = 0u;
      w0 = (unsigned int)__builtin_amdgcn_cvt_pk_fp8_f32(f0, f1, (int)w0, false);
      w0 = (unsigned int)__builtin_amdgcn_cvt_pk_fp8_f32(f2, f3, (int)w0, true);
      w1 = (unsigned int)__builtin_amdgcn_cvt_pk_fp8_f32(f4, f5, (int)w1, false);
      w1 = (unsigned int)__builtin_amdgcn_cvt_pk_fp8_f32(f6, f7, (int)w1, true);
      uint2 q;
      q.x = w0;
      q.y = w1;
      ((uint2*)(hq + (size_t)gr * HIDC))[ck] = q;
    }
  }
}

__device__ __forceinline__ int lbound_batch(const int* __restrict__ a, int key) {
  int lo = 0, hi = N_NODESC;
  while (lo < hi) {
    int mid = (lo + hi) >> 1;
    if (a[mid] < key) lo = mid + 1;
    else hi = mid;
  }
  return lo;
}

__global__ __launch_bounds__(128) void k_pool1(const unsigned short* __restrict__ hb,
                                               const int* __restrict__ batch,
                                               float* __restrict__ part) {
  int g = blockIdx.x / POOL_CHUNKS;
  int j = blockIdx.x % POOL_CHUNKS;
  int c = threadIdx.x;
  int lo = lbound_batch(batch, g);
  int hi = lbound_batch(batch, g + 1);
  int n = hi - lo;
  int ch = (n + POOL_CHUNKS - 1) / POOL_CHUNKS;
  int b = lo + j * ch;
  int e = b + ch;
  if (e > hi) e = hi;
  float s = 0.f, m = -INFINITY;
  for (int i = b; i < e; ++i) {
    unsigned short u = hb[(size_t)i * HIDC + c];
    float v = __uint_as_float((unsigned)u << 16);
    s += v;
    m = fmaxf(m, v);
  }
  size_t o = ((size_t)g * POOL_CHUNKS + j) * 256;
  part[o + c] = s;
  part[o + 128 + c] = m;
}

// fused: combine pool partials -> [add|max|mean] -> mlp1 -> mlp2 -> out. one block per graph.
__global__ __launch_bounds__(192) void k_tail(const float* __restrict__ part,
                                              const int* __restrict__ batch,
                                              const float* __restrict__ r1_w,
                                              const float* __restrict__ r1_b,
                                              const float* __restrict__ r2_w,
                                              const float* __restrict__ r2_b,
                                              float* __restrict__ out) {
  __shared__ float gv[384];
  __shared__ float g1[192];
  int g = blockIdx.x;
  int tid = threadIdx.x;
  if (tid < 128) {
    int c = tid;
    float s = 0.f, m = -INFINITY;
#pragma unroll
    for (int j = 0; j < POOL_CHUNKS; ++j) {
      size_t o = ((size_t)g * POOL_CHUNKS + j) * 256;
      s += part[o + c];
      m = fmaxf(m, part[o + 128 + c]);
    }
    int lo = lbound_batch(batch, g);
    int hi = lbound_batch(batch, g + 1);
    float cntf = (float)(hi - lo);
    gv[c] = s;
    gv[128 + c] = m;
    gv[256 + c] = s / fmaxf(cntf, 1.f);
  }
  __syncthreads();
  {
    int j = tid;
    float acc = r1_b[j];
    const float* wr = r1_w + (size_t)j * 384;
#pragma unroll 4
    for (int k = 0; k < 384; ++k) acc = fmaf(gv[k], wr[k], acc);
    g1[j] = (acc > 0.f) ? acc : 0.01f * acc;
  }
  __syncthreads();
  if (tid < OUT_DIMC) {
    int o = tid;
    float acc = r2_b[o];
    const float* wr = r2_w + o * 192;
    for (int k = 0; k < 192; ++k) acc = fmaf(g1[k], wr[k], acc);
    out[g * OUT_DIMC + o] = (acc > 0.f) ? acc : 0.01f * acc;
  }
}

extern "C" void kernel_launch(void* const* d_in, const int* in_sizes, int n_in,
                              void* d_out, int out_size, void* d_ws, size_t ws_size,
                              hipStream_t stream) {
  const float* x      = (const float*)d_in[0];
  const int*   ei     = (const int*)d_in[1];
  const int*   batch  = (const int*)d_in[2];
  const float* emb_w  = (const float*)d_in[3];
  const float* emb_b  = (const float*)d_in[4];
  const float* W      = (const float*)d_in[5];
  const float* asym_b = (const float*)d_in[6];
  const float* lin_w  = (const float*)d_in[7];
  const float* r1_w   = (const float*)d_in[8];
  const float* r1_b   = (const float*)d_in[9];
  const float* r2_w   = (const float*)d_in[10];
  const float* r2_b   = (const float*)d_in[11];
  float* out = (float*)d_out;

  char* ws = (char*)d_ws;
  size_t off = 0;
  auto alloc = [&](size_t bytes) -> char* {
    char* p = ws + off;
    off += (bytes + 255) & ~(size_t)255;
    return p;
  };
  unsigned short* hb  = (unsigned short*)alloc((size_t)N_NODESC * HIDC * 2);  // 25.6 MB
  unsigned char*  hq  = (unsigned char*)alloc((size_t)N_NODESC * HIDC);       // 12.8 MB
  unsigned short* ab  = (unsigned short*)alloc((size_t)N_NODESC * HIDC * 2);  // 25.6 MB
  unsigned short* MTP = (unsigned short*)alloc((size_t)32768 * 2);            // 64 KB
  unsigned short* EWP = (unsigned short*)alloc((size_t)8192 * 2);             // 16 KB
  int* rowptr   = (int*)alloc((size_t)(N_NODESC + 1) * 4);
  int* colidx   = (int*)alloc((size_t)N_EDGESC * 4);                // 6.4 MB
  unsigned int* ebuf = (unsigned int*)alloc((size_t)N_EDGESC * 4);  // 6.4 MB
  int* histg    = (int*)alloc((size_t)NHIST * 4);
  int* hoff     = (int*)alloc((size_t)NHIST * 4);
  int* bsum     = (int*)alloc((size_t)S1NB * 4);
  int* boff     = (int*)alloc((size_t)S1NB * 4);
  float* part   = (float*)alloc((size_t)N_GRAPHSC * POOL_CHUNKS * 256 * 4);
  (void)ws_size; (void)in_sizes; (void)n_in; (void)out_size;

  const int* srcv = ei;
  const int* dstv = ei + N_EDGESC;

  k_pack<<<(32768 + 8192 + 255) / 256, 256, 0, stream>>>(W, lin_w, emb_w, MTP, EWP);
  k_embed_mfma<<<UPD_NB, 256, 0, stream>>>(x, EWP, emb_b, hb, hq);
  k_hist<<<NBLK, 256, 0, stream>>>(dstv, histg);
  k_s1<<<S1NB, 256, 0, stream>>>(histg, bsum);
  k_s2<<<1, 256, 0, stream>>>(bsum, boff);
  k_s3<<<S1NB, 256, 0, stream>>>(histg, boff, hoff);
  k_scatter<<<NBLK, 256, 0, stream>>>(srcv, dstv, hoff, ebuf);
  k_csr<<<NBUK, 256, 0, stream>>>(ebuf, hoff, rowptr, colidx);
  for (int it = 0; it < NUM_ITERSC; ++it) {
    k_gather_q<<<N_NODESC / 4, 256, 0, stream>>>(hq, rowptr, colidx, ab);
    k_update_mfma<<<UPD_NB, 256, 0, stream>>>(hb, hq, ab, MTP, asym_b);
  }
  k_pool1<<<N_GRAPHSC * POOL_CHUNKS, 128, 0, stream>>>(hb, batch, part);
  k_tail<<<N_GRAPHSC, 192, 0, stream>>>(part, batch, r1_w, r1_b, r2_w, r2_b, out);
}

// Round 16
// 421.704 us; speedup vs baseline: 1.1601x; 1.0197x over previous
//
#include <hip/hip_runtime.h>
#include <hip/hip_bf16.h>
#include <math.h>

#define N_NODESC 100000
#define N_EDGESC 1600000
#define N_GRAPHSC 128
#define IN_DIMC 64
#define HIDC 128
#define OUT_DIMC 16
#define NUM_ITERSC 4
#define GAMMAC 0.1f
#define EPSC 0.1f
#define POOL_CHUNKS 8
#define UPD_NB ((N_NODESC + 63) / 64)

// bucketed CSR build
#define NBUK 98                         // ceil(100000/1024), bucket = dst>>10
#define EPB 4096                        // edges per hist/scatter block
#define NBLK ((N_EDGESC + EPB - 1) / EPB)   // 391
#define NHIST (NBUK * NBLK)             // 38318
#define S1NB ((NHIST + 255) / 256)      // 150

typedef __attribute__((ext_vector_type(8))) short bf16x8;
typedef __attribute__((ext_vector_type(4))) float f32x4;
typedef __attribute__((ext_vector_type(2))) float f32x2;

__device__ __forceinline__ unsigned short f2bf(float f) {
  unsigned int u = __float_as_uint(f);
  unsigned int r = (u + 0x7fffu + ((u >> 16) & 1u)) >> 16;  // RNE
  return (unsigned short)r;
}

__device__ __forceinline__ unsigned char f2q(float f) {  // f32 -> OCP e4m3 (HW RNE)
  unsigned int p = (unsigned int)__builtin_amdgcn_cvt_pk_fp8_f32(f, 0.f, 0, false);
  return (unsigned char)(p & 0xFFu);
}

__device__ __forceinline__ float tanh_fast(float x) {
  float a = fminf(fabsf(x), 15.0f);
  float e = __expf(2.0f * a);
  float r = (e - 1.0f) * __builtin_amdgcn_rcpf(e + 1.0f);
  return copysignf(r, x);
}

// Fused weight pack: MTP (update weights, 32768 elems) + EWP (embed weights, 8192 elems)
__global__ __launch_bounds__(256) void k_pack(const float* __restrict__ W,
                                              const float* __restrict__ lin_w,
                                              const float* __restrict__ emb_w,
                                              unsigned short* __restrict__ MTP,
                                              unsigned short* __restrict__ EWP) {
  int idx = blockIdx.x * 256 + threadIdx.x;
  if (idx < 32768) {
    int j = idx & 7;
    int lane = (idx >> 3) & 63;
    int t = idx >> 9;  // ct*8+kc
    int kc = t & 7, ct = t >> 3;
    int k = kc * 32 + (lane >> 4) * 8 + j;
    int c = ct * 16 + (lane & 15);
    float v;
    if (k < HIDC) v = W[c * HIDC + k] - W[k * HIDC + c] - ((k == c) ? GAMMAC : 0.0f);
    else v = lin_w[c * HIDC + (k - HIDC)];
    MTP[idx] = f2bf(v);
  } else if (idx < 32768 + 8192) {
    int i2 = idx - 32768;
    int j = i2 & 7;
    int lane = (i2 >> 3) & 63;
    int t = i2 >> 9;  // ct*2+kc
    int kc = t & 1, ct = t >> 1;
    int k = kc * 32 + (lane >> 4) * 8 + j;
    int c = ct * 16 + (lane & 15);
    EWP[i2] = f2bf(emb_w[c * IN_DIMC + k]);
  }
}

// hb = bf16(x @ emb_w.T + emb_b) via MFMA; also writes fp8 gather shadow hq
__global__ __launch_bounds__(256) void k_embed_mfma(const float* __restrict__ x,
                                                    const unsigned short* __restrict__ EWP,
                                                    const float* __restrict__ emb_b,
                                                    unsigned short* __restrict__ hb,
                                                    unsigned char* __restrict__ hq) {
  __shared__ __align__(16) unsigned char Xls[64 * 128];  // 64 rows x 64 bf16, swizzled
  int tid = threadIdx.x;
  int r0 = blockIdx.x * 64;
  for (int i = tid; i < 512; i += 256) {
    int row = i >> 3, ck = i & 7;
    int gr = r0 + row;
    uint4 v = make_uint4(0u, 0u, 0u, 0u);
    if (gr < N_NODESC) {
      const float* xp = x + (size_t)gr * IN_DIMC + ck * 8;
      float4 f0 = *(const float4*)xp;
      float4 f1 = *(const float4*)(xp + 4);
      v.x = (unsigned)f2bf(f0.x) | ((unsigned)f2bf(f0.y) << 16);
      v.y = (unsigned)f2bf(f0.z) | ((unsigned)f2bf(f0.w) << 16);
      v.z = (unsigned)f2bf(f1.x) | ((unsigned)f2bf(f1.y) << 16);
      v.w = (unsigned)f2bf(f1.z) | ((unsigned)f2bf(f1.w) << 16);
    }
    *(uint4*)(Xls + row * 128 + ((ck * 16) ^ ((row & 7) << 4))) = v;
  }
  __syncthreads();
  int lane = tid & 63, w = tid >> 6;
  int m = lane & 15, g = lane >> 4;
  int arow = w * 16 + m;
  bf16x8 a0 = *(const bf16x8*)(Xls + arow * 128 + ((g * 16) ^ ((arow & 7) << 4)));
  bf16x8 a1 = *(const bf16x8*)(Xls + arow * 128 + ((64 + g * 16) ^ ((arow & 7) << 4)));
  f32x4 acc[8];
#pragma unroll
  for (int ct = 0; ct < 8; ++ct) acc[ct] = (f32x4){0.f, 0.f, 0.f, 0.f};
#pragma unroll
  for (int ct = 0; ct < 8; ++ct) {
    bf16x8 b0 = *(const bf16x8*)(EWP + ((size_t)((ct * 2 + 0) * 64 + lane)) * 8);
    bf16x8 b1 = *(const bf16x8*)(EWP + ((size_t)((ct * 2 + 1) * 64 + lane)) * 8);
    acc[ct] = __builtin_amdgcn_mfma_f32_16x16x32_bf16(a0, b0, acc[ct], 0, 0, 0);
    acc[ct] = __builtin_amdgcn_mfma_f32_16x16x32_bf16(a1, b1, acc[ct], 0, 0, 0);
  }
#pragma unroll
  for (int ct = 0; ct < 8; ++ct) {
    int col = ct * 16 + m;
    float bias = emb_b[col];
#pragma unroll
    for (int j = 0; j < 4; ++j) {
      int grow = r0 + w * 16 + g * 4 + j;
      if (grow < N_NODESC) {
        float val = acc[ct][j] + bias;
        hb[(size_t)grow * HIDC + col] = f2bf(val);
        hq[(size_t)grow * HIDC + col] = f2q(val);
      }
    }
  }
}

// ---- bucketed CSR build ----
__global__ __launch_bounds__(256) void k_hist(const int* __restrict__ dst, int* __restrict__ histg) {
  __shared__ int hl[NBUK];
  int tid = threadIdx.x;
  for (int i = tid; i < NBUK; i += 256) hl[i] = 0;
  __syncthreads();
  int base = blockIdx.x * EPB;
  int end = base + EPB;
  if (end > N_EDGESC) end = N_EDGESC;
  for (int e = base + tid; e < end; e += 256) atomicAdd(&hl[dst[e] >> 10], 1);
  __syncthreads();
  for (int i = tid; i < NBUK; i += 256) histg[i * NBLK + blockIdx.x] = hl[i];
}

__global__ __launch_bounds__(256) void k_s1(const int* __restrict__ in, int* __restrict__ bsum) {
  __shared__ int red[256];
  int tid = threadIdx.x;
  int i = blockIdx.x * 256 + tid;
  red[tid] = (i < NHIST) ? in[i] : 0;
  __syncthreads();
#pragma unroll
  for (int off = 128; off > 0; off >>= 1) {
    if (tid < off) red[tid] += red[tid + off];
    __syncthreads();
  }
  if (tid == 0) bsum[blockIdx.x] = red[0];
}

__global__ __launch_bounds__(256) void k_s2(int* __restrict__ bsum, int* __restrict__ boff) {
  __shared__ int buf[256];
  int tid = threadIdx.x;
  int v = (tid < S1NB) ? bsum[tid] : 0;
  buf[tid] = v;
  __syncthreads();
  for (int off = 1; off < 256; off <<= 1) {
    int t = (tid >= off) ? buf[tid - off] : 0;
    __syncthreads();
    buf[tid] += t;
    __syncthreads();
  }
  if (tid < S1NB) boff[tid] = buf[tid] - v;
}

__global__ __launch_bounds__(256) void k_s3(const int* __restrict__ in, const int* __restrict__ boff,
                                            int* __restrict__ out) {
  __shared__ int buf[256];
  int tid = threadIdx.x;
  int i = blockIdx.x * 256 + tid;
  int v = (i < NHIST) ? in[i] : 0;
  buf[tid] = v;
  __syncthreads();
  for (int off = 1; off < 256; off <<= 1) {
    int t = (tid >= off) ? buf[tid - off] : 0;
    __syncthreads();
    buf[tid] += t;
    __syncthreads();
  }
  if (i < NHIST) out[i] = boff[blockIdx.x] + buf[tid] - v;
}

__global__ __launch_bounds__(256) void k_scatter(const int* __restrict__ src, const int* __restrict__ dst,
                                                 const int* __restrict__ hoff, unsigned int* __restrict__ ebuf) {
  __shared__ int cur[NBUK];
  int tid = threadIdx.x;
  for (int i = tid; i < NBUK; i += 256) cur[i] = hoff[i * NBLK + blockIdx.x];
  __syncthreads();
  int base = blockIdx.x * EPB;
  int end = base + EPB;
  if (end > N_EDGESC) end = N_EDGESC;
  for (int e = base + tid; e < end; e += 256) {
    int d = dst[e];
    int bu = d >> 10;
    int pos = atomicAdd(&cur[bu], 1);
    ebuf[pos] = ((unsigned int)(d & 1023) << 17) | (unsigned int)src[e];
  }
}

// colidx stores BYTE OFFSETS into hq (src * 128) for address-free gather loads
__global__ __launch_bounds__(256) void k_csr(const unsigned int* __restrict__ ebuf,
                                             const int* __restrict__ hoff,
                                             int* __restrict__ rowptr, int* __restrict__ colidx) {
  __shared__ int lcnt[1024];
  __shared__ int lcur[1024];
  __shared__ int ssum[256];
  int b = blockIdx.x, tid = threadIdx.x;
  int ebeg = hoff[b * NBLK];
  int eend = (b + 1 < NBUK) ? hoff[(b + 1) * NBLK] : N_EDGESC;
  for (int i = tid; i < 1024; i += 256) lcnt[i] = 0;
  __syncthreads();
  for (int e = ebeg + tid; e < eend; e += 256) atomicAdd(&lcnt[ebuf[e] >> 17], 1);
  __syncthreads();
  int c0 = lcnt[tid * 4 + 0], c1 = lcnt[tid * 4 + 1], c2 = lcnt[tid * 4 + 2], c3 = lcnt[tid * 4 + 3];
  int s = c0 + c1 + c2 + c3;
  ssum[tid] = s;
  __syncthreads();
  for (int off = 1; off < 256; off <<= 1) {
    int t = (tid >= off) ? ssum[tid - off] : 0;
    __syncthreads();
    ssum[tid] += t;
    __syncthreads();
  }
  int excl = ssum[tid] - s;
  int node0 = (b << 10) + tid * 4;
  int ex = excl;
  lcur[tid * 4 + 0] = ex; if (node0 + 0 < N_NODESC) rowptr[node0 + 0] = ebeg + ex; ex += c0;
  lcur[tid * 4 + 1] = ex; if (node0 + 1 < N_NODESC) rowptr[node0 + 1] = ebeg + ex; ex += c1;
  lcur[tid * 4 + 2] = ex; if (node0 + 2 < N_NODESC) rowptr[node0 + 2] = ebeg + ex; ex += c2;
  lcur[tid * 4 + 3] = ex; if (node0 + 3 < N_NODESC) rowptr[node0 + 3] = ebeg + ex;
  __syncthreads();
  for (int e = ebeg + tid; e < eend; e += 256) {
    unsigned int u = ebuf[e];
    int pos = atomicAdd(&lcur[u >> 17], 1);
    colidx[ebeg + pos] = (int)((u & 0x1FFFFu) << 7);  // byte offset: src * HIDC
  }
  if (b == 0 && tid == 0) rowptr[N_NODESC] = N_EDGESC;
}

// agg over in-edges from fp8 shadow; one wave per node.
// lane = (edge slot g 0..3) x (8-col chunk l 0..15); uint2 = 8B fp8 per lane.
// colidx preloaded per <=64-edge window, broadcast via __shfl (wave-uniform only).
__global__ __launch_bounds__(256) void k_gather_q(const unsigned char* __restrict__ hq,
                                                  const int* __restrict__ rowptr,
                                                  const int* __restrict__ colidx,
                                                  unsigned short* __restrict__ aggb) {
  int node = blockIdx.x * 4 + (threadIdx.x >> 6);
  int lane = threadIdx.x & 63;
  if (node >= N_NODESC) return;
  int g = lane >> 4;   // edge slot 0..3
  int l = lane & 15;   // 8B chunk 0..15
  int beg = rowptr[node], end = rowptr[node + 1];
  f32x2 acc2[4];
#pragma unroll
  for (int i = 0; i < 4; ++i) acc2[i] = (f32x2){0.f, 0.f};
  int wbase = beg;
  int cv = (wbase + lane < end) ? colidx[wbase + lane] : 0;
  int e = beg;
  for (; e + 16 <= end; e += 16) {   // all conditions wave-uniform
    if (e + 16 > wbase + 64) {
      wbase = e;
      cv = (wbase + lane < end) ? colidx[wbase + lane] : 0;
    }
    int i0 = e - wbase;
    int o0 = __shfl(cv, i0 + g);
    int o1 = __shfl(cv, i0 + 4 + g);
    int o2 = __shfl(cv, i0 + 8 + g);
    int o3 = __shfl(cv, i0 + 12 + g);
    uint2 u0 = ((const uint2*)(hq + (size_t)(unsigned)o0))[l];
    uint2 u1 = ((const uint2*)(hq + (size_t)(unsigned)o1))[l];
    uint2 u2 = ((const uint2*)(hq + (size_t)(unsigned)o2))[l];
    uint2 u3 = ((const uint2*)(hq + (size_t)(unsigned)o3))[l];
    acc2[0] += __builtin_amdgcn_cvt_pk_f32_fp8((int)u0.x, false);
    acc2[1] += __builtin_amdgcn_cvt_pk_f32_fp8((int)u0.x, true);
    acc2[2] += __builtin_amdgcn_cvt_pk_f32_fp8((int)u0.y, false);
    acc2[3] += __builtin_amdgcn_cvt_pk_f32_fp8((int)u0.y, true);
    acc2[0] += __builtin_amdgcn_cvt_pk_f32_fp8((int)u1.x, false);
    acc2[1] += __builtin_amdgcn_cvt_pk_f32_fp8((int)u1.x, true);
    acc2[2] += __builtin_amdgcn_cvt_pk_f32_fp8((int)u1.y, false);
    acc2[3] += __builtin_amdgcn_cvt_pk_f32_fp8((int)u1.y, true);
    acc2[0] += __builtin_amdgcn_cvt_pk_f32_fp8((int)u2.x, false);
    acc2[1] += __builtin_amdgcn_cvt_pk_f32_fp8((int)u2.x, true);
    acc2[2] += __builtin_amdgcn_cvt_pk_f32_fp8((int)u2.y, false);
    acc2[3] += __builtin_amdgcn_cvt_pk_f32_fp8((int)u2.y, true);
    acc2[0] += __builtin_amdgcn_cvt_pk_f32_fp8((int)u3.x, false);
    acc2[1] += __builtin_amdgcn_cvt_pk_f32_fp8((int)u3.x, true);
    acc2[2] += __builtin_amdgcn_cvt_pk_f32_fp8((int)u3.y, false);
    acc2[3] += __builtin_amdgcn_cvt_pk_f32_fp8((int)u3.y, true);
  }
  if (e + 8 <= end) {                // wave-uniform
    if (e + 8 > wbase + 64) {
      wbase = e;
      cv = (wbase + lane < end) ? colidx[wbase + lane] : 0;
    }
    int i0 = e - wbase;
    int o0 = __shfl(cv, i0 + g);
    int o1 = __shfl(cv, i0 + 4 + g);
    uint2 u0 = ((const uint2*)(hq + (size_t)(unsigned)o0))[l];
    uint2 u1 = ((const uint2*)(hq + (size_t)(unsigned)o1))[l];
    acc2[0] += __builtin_amdgcn_cvt_pk_f32_fp8((int)u0.x, false);
    acc2[1] += __builtin_amdgcn_cvt_pk_f32_fp8((int)u0.x, true);
    acc2[2] += __builtin_amdgcn_cvt_pk_f32_fp8((int)u0.y, false);
    acc2[3] += __builtin_amdgcn_cvt_pk_f32_fp8((int)u0.y, true);
    acc2[0] += __builtin_amdgcn_cvt_pk_f32_fp8((int)u1.x, false);
    acc2[1] += __builtin_amdgcn_cvt_pk_f32_fp8((int)u1.x, true);
    acc2[2] += __builtin_amdgcn_cvt_pk_f32_fp8((int)u1.y, false);
    acc2[3] += __builtin_amdgcn_cvt_pk_f32_fp8((int)u1.y, true);
    e += 8;
  }
  // tail (up to 7 edges): shfl hoisted OUT of the divergent guard
  if (e < end) {                     // wave-uniform
    if (e + 8 > wbase + 64) {
      wbase = e;
      cv = (wbase + lane < end) ? colidx[wbase + lane] : 0;
    }
#pragma unroll
    for (int t = 0; t < 2; ++t) {
      int eg = e + t * 4 + g;
      int o0 = __shfl(cv, (eg - wbase) & 63);  // executed by ALL lanes
      if (eg < end) {                          // divergence only on load+acc
        uint2 u0 = ((const uint2*)(hq + (size_t)(unsigned)o0))[l];
        acc2[0] += __builtin_amdgcn_cvt_pk_f32_fp8((int)u0.x, false);
        acc2[1] += __builtin_amdgcn_cvt_pk_f32_fp8((int)u0.x, true);
        acc2[2] += __builtin_amdgcn_cvt_pk_f32_fp8((int)u0.y, false);
        acc2[3] += __builtin_amdgcn_cvt_pk_f32_fp8((int)u0.y, true);
      }
    }
  }
  // reduce across the 4 edge slots
#pragma unroll
  for (int i = 0; i < 4; ++i) {
    acc2[i].x += __shfl_xor(acc2[i].x, 16);
    acc2[i].y += __shfl_xor(acc2[i].y, 16);
    acc2[i].x += __shfl_xor(acc2[i].x, 32);
    acc2[i].y += __shfl_xor(acc2[i].y, 32);
  }
  if (g == 0) {
    uint4 o;
    o.x = (unsigned)f2bf(acc2[0].x) | ((unsigned)f2bf(acc2[0].y) << 16);
    o.y = (unsigned)f2bf(acc2[1].x) | ((unsigned)f2bf(acc2[1].y) << 16);
    o.z = (unsigned)f2bf(acc2[2].x) | ((unsigned)f2bf(acc2[2].y) << 16);
    o.w = (unsigned)f2bf(acc2[3].x) | ((unsigned)f2bf(acc2[3].y) << 16);
    ((uint4*)(aggb + (size_t)node * HIDC))[l] = o;
  }
}

// conv = [hb|aggb] @ M^T via MFMA bf16 (K=256); hb = bf16(hb + eps*tanh(conv+b)) in place;
// refresh fp8 shadow hq. LDS holds ONLY the hb half (16 KB, swizzled) — agg A-frags load
// directly from global (L2-hot, 1KB/instruction coalescing). Epilogue reads h_old from LDS
// and writes the result back to the SAME slot (wave-private rows, single-touch, no barrier),
// then vectorized uint4/uint2 copy-out.
__global__ __launch_bounds__(256) void k_update_mfma(unsigned short* __restrict__ hb,
                                                     unsigned char* __restrict__ hq,
                                                     const unsigned short* __restrict__ aggb,
                                                     const unsigned short* __restrict__ MTP,
                                                     const float* __restrict__ asym_b) {
  __shared__ __align__(16) unsigned char Als[64 * 256];  // 64 rows x 128 bf16 (hb), swizzled
  int tid = threadIdx.x;
  int r0 = blockIdx.x * 64;
  for (int i = tid; i < 1024; i += 256) {
    int row = i >> 4;
    int ck = i & 15;
    int gr = r0 + row;
    uint4 v = make_uint4(0u, 0u, 0u, 0u);
    if (gr < N_NODESC) v = ((const uint4*)(hb + (size_t)gr * HIDC))[ck];
    *(uint4*)(Als + row * 256 + ((ck * 16) ^ ((row & 7) << 4))) = v;
  }
  __syncthreads();
  int lane = tid & 63, w = tid >> 6;
  int m = lane & 15, g = lane >> 4;
  int arow = w * 16 + m;
  int garow = r0 + arow;
  if (garow >= N_NODESC) garow = N_NODESC - 1;  // clamp (results for pad rows discarded)
  bf16x8 a[8];
#pragma unroll
  for (int kc = 0; kc < 4; ++kc) {
    a[kc] = *(const bf16x8*)(Als + arow * 256 + ((kc * 64 + g * 16) ^ ((arow & 7) << 4)));
  }
#pragma unroll
  for (int kc = 4; kc < 8; ++kc) {
    a[kc] = *(const bf16x8*)(aggb + (size_t)garow * HIDC + (kc - 4) * 32 + g * 8);
  }
  f32x4 acc[8];
#pragma unroll
  for (int ct = 0; ct < 8; ++ct) acc[ct] = (f32x4){0.f, 0.f, 0.f, 0.f};
#pragma unroll
  for (int ct = 0; ct < 8; ++ct) {
#pragma unroll
    for (int kc = 0; kc < 8; ++kc) {
      bf16x8 b = *(const bf16x8*)(MTP + ((size_t)((ct * 8 + kc) * 64 + lane)) * 8);
      acc[ct] = __builtin_amdgcn_mfma_f32_16x16x32_bf16(a[kc], b, acc[ct], 0, 0, 0);
    }
  }
  // epilogue: read h_old from LDS slot, write result back to the SAME slot (wave-private)
#pragma unroll
  for (int ct = 0; ct < 8; ++ct) {
    int col = ct * 16 + m;
    float bias = asym_b[col];
    int lb = col * 2;  // byte offset of col within a 256B row
#pragma unroll
    for (int j = 0; j < 4; ++j) {
      int lrow = w * 16 + g * 4 + j;
      int haddr = lrow * 256 + (((lb & ~15) ^ ((lrow & 7) << 4)) | (lb & 15));
      unsigned short hu = *(const unsigned short*)(Als + haddr);
      float hold = __uint_as_float((unsigned)hu << 16);
      float val = hold + EPSC * tanh_fast(acc[ct][j] + bias);
      *(unsigned short*)(Als + haddr) = f2bf(val);
    }
  }
  // copy-out: wave w copies its 16 rows; uint4 hb stores + uint2 hq stores, coalesced
#pragma unroll
  for (int k = 0; k < 4; ++k) {
    int idx = k * 64 + lane;           // 0..255 per wave
    int row = w * 16 + (idx >> 4);
    int ck = idx & 15;                 // 16B chunk
    int gr = r0 + row;
    if (gr < N_NODESC) {
      uint4 v = *(const uint4*)(Als + row * 256 + ((ck * 16) ^ ((row & 7) << 4)));
      ((uint4*)(hb + (size_t)gr * HIDC))[ck] = v;
      float f0 = __uint_as_float(v.x << 16), f1 = __uint_as_float(v.x & 0xffff0000u);
      float f2 = __uint_as_float(v.y << 16), f3 = __uint_as_float(v.y & 0xffff0000u);
      float f4 = __uint_as_float(v.z << 16), f5 = __uint_as_float(v.z & 0xffff0000u);
      float f6 = __uint_as_float(v.w << 16), f7 = __uint_as_float(v.w & 0xffff0000u);
      unsigned int w0 = 0u, w1 = 0u;
      w0 = (unsigned int)__builtin_amdgcn_cvt_pk_fp8_f32(f0, f1, (int)w0, false);
      w0 = (unsigned int)__builtin_amdgcn_cvt_pk_fp8_f32(f2, f3, (int)w0, true);
      w1 = (unsigned int)__builtin_amdgcn_cvt_pk_fp8_f32(f4, f5, (int)w1, false);
      w1 = (unsigned int)__builtin_amdgcn_cvt_pk_fp8_f32(f6, f7, (int)w1, true);
      uint2 q;
      q.x = w0;
      q.y = w1;
      ((uint2*)(hq + (size_t)gr * HIDC))[ck] = q;
    }
  }
}

__device__ __forceinline__ int lbound_batch(const int* __restrict__ a, int key) {
  int lo = 0, hi = N_NODESC;
  while (lo < hi) {
    int mid = (lo + hi) >> 1;
    if (a[mid] < key) lo = mid + 1;
    else hi = mid;
  }
  return lo;
}

__global__ __launch_bounds__(128) void k_pool1(const unsigned short* __restrict__ hb,
                                               const int* __restrict__ batch,
                                               float* __restrict__ part) {
  int g = blockIdx.x / POOL_CHUNKS;
  int j = blockIdx.x % POOL_CHUNKS;
  int c = threadIdx.x;
  int lo = lbound_batch(batch, g);
  int hi = lbound_batch(batch, g + 1);
  int n = hi - lo;
  int ch = (n + POOL_CHUNKS - 1) / POOL_CHUNKS;
  int b = lo + j * ch;
  int e = b + ch;
  if (e > hi) e = hi;
  float s = 0.f, m = -INFINITY;
  for (int i = b; i < e; ++i) {
    unsigned short u = hb[(size_t)i * HIDC + c];
    float v = __uint_as_float((unsigned)u << 16);
    s += v;
    m = fmaxf(m, v);
  }
  size_t o = ((size_t)g * POOL_CHUNKS + j) * 256;
  part[o + c] = s;
  part[o + 128 + c] = m;
}

// fused: combine pool partials -> [add|max|mean] -> mlp1 -> mlp2 -> out. one block per graph.
__global__ __launch_bounds__(192) void k_tail(const float* __restrict__ part,
                                              const int* __restrict__ batch,
                                              const float* __restrict__ r1_w,
                                              const float* __restrict__ r1_b,
                                              const float* __restrict__ r2_w,
                                              const float* __restrict__ r2_b,
                                              float* __restrict__ out) {
  __shared__ float gv[384];
  __shared__ float g1[192];
  int g = blockIdx.x;
  int tid = threadIdx.x;
  if (tid < 128) {
    int c = tid;
    float s = 0.f, m = -INFINITY;
#pragma unroll
    for (int j = 0; j < POOL_CHUNKS; ++j) {
      size_t o = ((size_t)g * POOL_CHUNKS + j) * 256;
      s += part[o + c];
      m = fmaxf(m, part[o + 128 + c]);
    }
    int lo = lbound_batch(batch, g);
    int hi = lbound_batch(batch, g + 1);
    float cntf = (float)(hi - lo);
    gv[c] = s;
    gv[128 + c] = m;
    gv[256 + c] = s / fmaxf(cntf, 1.f);
  }
  __syncthreads();
  {
    int j = tid;
    float acc = r1_b[j];
    const float* wr = r1_w + (size_t)j * 384;
#pragma unroll 4
    for (int k = 0; k < 384; ++k) acc = fmaf(gv[k], wr[k], acc);
    g1[j] = (acc > 0.f) ? acc : 0.01f * acc;
  }
  __syncthreads();
  if (tid < OUT_DIMC) {
    int o = tid;
    float acc = r2_b[o];
    const float* wr = r2_w + o * 192;
    for (int k = 0; k < 192; ++k) acc = fmaf(g1[k], wr[k], acc);
    out[g * OUT_DIMC + o] = (acc > 0.f) ? acc : 0.01f * acc;
  }
}

extern "C" void kernel_launch(void* const* d_in, const int* in_sizes, int n_in,
                              void* d_out, int out_size, void* d_ws, size_t ws_size,
                              hipStream_t stream) {
  const float* x      = (const float*)d_in[0];
  const int*   ei     = (const int*)d_in[1];
  const int*   batch  = (const int*)d_in[2];
  const float* emb_w  = (const float*)d_in[3];
  const float* emb_b  = (const float*)d_in[4];
  const float* W      = (const float*)d_in[5];
  const float* asym_b = (const float*)d_in[6];
  const float* lin_w  = (const float*)d_in[7];
  const float* r1_w   = (const float*)d_in[8];
  const float* r1_b   = (const float*)d_in[9];
  const float* r2_w   = (const float*)d_in[10];
  const float* r2_b   = (const float*)d_in[11];
  float* out = (float*)d_out;

  char* ws = (char*)d_ws;
  size_t off = 0;
  auto alloc = [&](size_t bytes) -> char* {
    char* p = ws + off;
    off += (bytes + 255) & ~(size_t)255;
    return p;
  };
  unsigned short* hb  = (unsigned short*)alloc((size_t)N_NODESC * HIDC * 2);  // 25.6 MB
  unsigned char*  hq  = (unsigned char*)alloc((size_t)N_NODESC * HIDC);       // 12.8 MB
  unsigned short* ab  = (unsigned short*)alloc((size_t)N_NODESC * HIDC * 2);  // 25.6 MB
  unsigned short* MTP = (unsigned short*)alloc((size_t)32768 * 2);            // 64 KB
  unsigned short* EWP = (unsigned short*)alloc((size_t)8192 * 2);             // 16 KB
  int* rowptr   = (int*)alloc((size_t)(N_NODESC + 1) * 4);
  int* colidx   = (int*)alloc((size_t)N_EDGESC * 4);                // 6.4 MB
  unsigned int* ebuf = (unsigned int*)alloc((size_t)N_EDGESC * 4);  // 6.4 MB
  int* histg    = (int*)alloc((size_t)NHIST * 4);
  int* hoff     = (int*)alloc((size_t)NHIST * 4);
  int* bsum     = (int*)alloc((size_t)S1NB * 4);
  int* boff     = (int*)alloc((size_t)S1NB * 4);
  float* part   = (float*)alloc((size_t)N_GRAPHSC * POOL_CHUNKS * 256 * 4);
  (void)ws_size; (void)in_sizes; (void)n_in; (void)out_size;

  const int* srcv = ei;
  const int* dstv = ei + N_EDGESC;

  k_pack<<<(32768 + 8192 + 255) / 256, 256, 0, stream>>>(W, lin_w, emb_w, MTP, EWP);
  k_embed_mfma<<<UPD_NB, 256, 0, stream>>>(x, EWP, emb_b, hb, hq);
  k_hist<<<NBLK, 256, 0, stream>>>(dstv, histg);
  k_s1<<<S1NB, 256, 0, stream>>>(histg, bsum);
  k_s2<<<1, 256, 0, stream>>>(bsum, boff);
  k_s3<<<S1NB, 256, 0, stream>>>(histg, boff, hoff);
  k_scatter<<<NBLK, 256, 0, stream>>>(srcv, dstv, hoff, ebuf);
  k_csr<<<NBUK, 256, 0, stream>>>(ebuf, hoff, rowptr, colidx);
  for (int it = 0; it < NUM_ITERSC; ++it) {
    k_gather_q<<<N_NODESC / 4, 256, 0, stream>>>(hq, rowptr, colidx, ab);
    k_update_mfma<<<UPD_NB, 256, 0, stream>>>(hb, hq, ab, MTP, asym_b);
  }
  k_pool1<<<N_GRAPHSC * POOL_CHUNKS, 128, 0, stream>>>(hb, batch, part);
  k_tail<<<N_GRAPHSC, 192, 0, stream>>>(part, batch, r1_w, r1_b, r2_w, r2_b, out);
}

// Round 18
// 420.370 us; speedup vs baseline: 1.1638x; 1.0032x over previous
//
#include <hip/hip_runtime.h>
#include <hip/hip_bf16.h>
#include <math.h>

#define N_NODESC 100000
#define N_EDGESC 1600000
#define N_GRAPHSC 128
#define IN_DIMC 64
#define HIDC 128
#define OUT_DIMC 16
#define NUM_ITERSC 4
#define GAMMAC 0.1f
#define EPSC 0.1f
#define POOL_CHUNKS 8
#define UPD_NB ((N_NODESC + 63) / 64)

// bucketed CSR build
#define NBUK 98                         // ceil(100000/1024), bucket = dst>>10
#define EPB 4096                        // edges per hist/scatter block
#define NBLK ((N_EDGESC + EPB - 1) / EPB)   // 391
#define NHIST (NBUK * NBLK)             // 38318
#define S1NB ((NHIST + 255) / 256)      // 150

typedef __attribute__((ext_vector_type(8))) short bf16x8;
typedef __attribute__((ext_vector_type(4))) float f32x4;
typedef __attribute__((ext_vector_type(2))) float f32x2;

__device__ __forceinline__ unsigned short f2bf(float f) {
  unsigned int u = __float_as_uint(f);
  unsigned int r = (u + 0x7fffu + ((u >> 16) & 1u)) >> 16;  // RNE
  return (unsigned short)r;
}

__device__ __forceinline__ unsigned char f2q(float f) {  // f32 -> OCP e4m3 (HW RNE)
  unsigned int p = (unsigned int)__builtin_amdgcn_cvt_pk_fp8_f32(f, 0.f, 0, false);
  return (unsigned char)(p & 0xFFu);
}

__device__ __forceinline__ float tanh_fast(float x) {
  float a = fminf(fabsf(x), 15.0f);
  float e = __expf(2.0f * a);
  float r = (e - 1.0f) * __builtin_amdgcn_rcpf(e + 1.0f);
  return copysignf(r, x);
}

// Fused weight pack: MTP (update weights, 32768 elems) + EWP (embed weights, 8192 elems)
__global__ __launch_bounds__(256) void k_pack(const float* __restrict__ W,
                                              const float* __restrict__ lin_w,
                                              const float* __restrict__ emb_w,
                                              unsigned short* __restrict__ MTP,
                                              unsigned short* __restrict__ EWP) {
  int idx = blockIdx.x * 256 + threadIdx.x;
  if (idx < 32768) {
    int j = idx & 7;
    int lane = (idx >> 3) & 63;
    int t = idx >> 9;  // ct*8+kc
    int kc = t & 7, ct = t >> 3;
    int k = kc * 32 + (lane >> 4) * 8 + j;
    int c = ct * 16 + (lane & 15);
    float v;
    if (k < HIDC) v = W[c * HIDC + k] - W[k * HIDC + c] - ((k == c) ? GAMMAC : 0.0f);
    else v = lin_w[c * HIDC + (k - HIDC)];
    MTP[idx] = f2bf(v);
  } else if (idx < 32768 + 8192) {
    int i2 = idx - 32768;
    int j = i2 & 7;
    int lane = (i2 >> 3) & 63;
    int t = i2 >> 9;  // ct*2+kc
    int kc = t & 1, ct = t >> 1;
    int k = kc * 32 + (lane >> 4) * 8 + j;
    int c = ct * 16 + (lane & 15);
    EWP[i2] = f2bf(emb_w[c * IN_DIMC + k]);
  }
}

// hb = bf16(x @ emb_w.T + emb_b) via MFMA; also writes fp8 gather shadow hq
__global__ __launch_bounds__(256) void k_embed_mfma(const float* __restrict__ x,
                                                    const unsigned short* __restrict__ EWP,
                                                    const float* __restrict__ emb_b,
                                                    unsigned short* __restrict__ hb,
                                                    unsigned char* __restrict__ hq) {
  __shared__ __align__(16) unsigned char Xls[64 * 128];  // 64 rows x 64 bf16, swizzled
  int tid = threadIdx.x;
  int r0 = blockIdx.x * 64;
  for (int i = tid; i < 512; i += 256) {
    int row = i >> 3, ck = i & 7;
    int gr = r0 + row;
    uint4 v = make_uint4(0u, 0u, 0u, 0u);
    if (gr < N_NODESC) {
      const float* xp = x + (size_t)gr * IN_DIMC + ck * 8;
      float4 f0 = *(const float4*)xp;
      float4 f1 = *(const float4*)(xp + 4);
      v.x = (unsigned)f2bf(f0.x) | ((unsigned)f2bf(f0.y) << 16);
      v.y = (unsigned)f2bf(f0.z) | ((unsigned)f2bf(f0.w) << 16);
      v.z = (unsigned)f2bf(f1.x) | ((unsigned)f2bf(f1.y) << 16);
      v.w = (unsigned)f2bf(f1.z) | ((unsigned)f2bf(f1.w) << 16);
    }
    *(uint4*)(Xls + row * 128 + ((ck * 16) ^ ((row & 7) << 4))) = v;
  }
  __syncthreads();
  int lane = tid & 63, w = tid >> 6;
  int m = lane & 15, g = lane >> 4;
  int arow = w * 16 + m;
  bf16x8 a0 = *(const bf16x8*)(Xls + arow * 128 + ((g * 16) ^ ((arow & 7) << 4)));
  bf16x8 a1 = *(const bf16x8*)(Xls + arow * 128 + ((64 + g * 16) ^ ((arow & 7) << 4)));
  f32x4 acc[8];
#pragma unroll
  for (int ct = 0; ct < 8; ++ct) acc[ct] = (f32x4){0.f, 0.f, 0.f, 0.f};
#pragma unroll
  for (int ct = 0; ct < 8; ++ct) {
    bf16x8 b0 = *(const bf16x8*)(EWP + ((size_t)((ct * 2 + 0) * 64 + lane)) * 8);
    bf16x8 b1 = *(const bf16x8*)(EWP + ((size_t)((ct * 2 + 1) * 64 + lane)) * 8);
    acc[ct] = __builtin_amdgcn_mfma_f32_16x16x32_bf16(a0, b0, acc[ct], 0, 0, 0);
    acc[ct] = __builtin_amdgcn_mfma_f32_16x16x32_bf16(a1, b1, acc[ct], 0, 0, 0);
  }
#pragma unroll
  for (int ct = 0; ct < 8; ++ct) {
    int col = ct * 16 + m;
    float bias = emb_b[col];
#pragma unroll
    for (int j = 0; j < 4; ++j) {
      int grow = r0 + w * 16 + g * 4 + j;
      if (grow < N_NODESC) {
        float val = acc[ct][j] + bias;
        hb[(size_t)grow * HIDC + col] = f2bf(val);
        hq[(size_t)grow * HIDC + col] = f2q(val);
      }
    }
  }
}

// ---- bucketed CSR build ----
__global__ __launch_bounds__(256) void k_hist(const int* __restrict__ dst, int* __restrict__ histg) {
  __shared__ int hl[NBUK];
  int tid = threadIdx.x;
  for (int i = tid; i < NBUK; i += 256) hl[i] = 0;
  __syncthreads();
  int base = blockIdx.x * EPB;
  int end = base + EPB;
  if (end > N_EDGESC) end = N_EDGESC;
  for (int e = base + tid; e < end; e += 256) atomicAdd(&hl[dst[e] >> 10], 1);
  __syncthreads();
  for (int i = tid; i < NBUK; i += 256) histg[i * NBLK + blockIdx.x] = hl[i];
}

__global__ __launch_bounds__(256) void k_s1(const int* __restrict__ in, int* __restrict__ bsum) {
  __shared__ int red[256];
  int tid = threadIdx.x;
  int i = blockIdx.x * 256 + tid;
  red[tid] = (i < NHIST) ? in[i] : 0;
  __syncthreads();
#pragma unroll
  for (int off = 128; off > 0; off >>= 1) {
    if (tid < off) red[tid] += red[tid + off];
    __syncthreads();
  }
  if (tid == 0) bsum[blockIdx.x] = red[0];
}

__global__ __launch_bounds__(256) void k_s2(int* __restrict__ bsum, int* __restrict__ boff) {
  __shared__ int buf[256];
  int tid = threadIdx.x;
  int v = (tid < S1NB) ? bsum[tid] : 0;
  buf[tid] = v;
  __syncthreads();
  for (int off = 1; off < 256; off <<= 1) {
    int t = (tid >= off) ? buf[tid - off] : 0;
    __syncthreads();
    buf[tid] += t;
    __syncthreads();
  }
  if (tid < S1NB) boff[tid] = buf[tid] - v;
}

__global__ __launch_bounds__(256) void k_s3(const int* __restrict__ in, const int* __restrict__ boff,
                                            int* __restrict__ out) {
  __shared__ int buf[256];
  int tid = threadIdx.x;
  int i = blockIdx.x * 256 + tid;
  int v = (i < NHIST) ? in[i] : 0;
  buf[tid] = v;
  __syncthreads();
  for (int off = 1; off < 256; off <<= 1) {
    int t = (tid >= off) ? buf[tid - off] : 0;
    __syncthreads();
    buf[tid] += t;
    __syncthreads();
  }
  if (i < NHIST) out[i] = boff[blockIdx.x] + buf[tid] - v;
}

__global__ __launch_bounds__(256) void k_scatter(const int* __restrict__ src, const int* __restrict__ dst,
                                                 const int* __restrict__ hoff, unsigned int* __restrict__ ebuf) {
  __shared__ int cur[NBUK];
  int tid = threadIdx.x;
  for (int i = tid; i < NBUK; i += 256) cur[i] = hoff[i * NBLK + blockIdx.x];
  __syncthreads();
  int base = blockIdx.x * EPB;
  int end = base + EPB;
  if (end > N_EDGESC) end = N_EDGESC;
  for (int e = base + tid; e < end; e += 256) {
    int d = dst[e];
    int bu = d >> 10;
    int pos = atomicAdd(&cur[bu], 1);
    ebuf[pos] = ((unsigned int)(d & 1023) << 17) | (unsigned int)src[e];
  }
}

// colidx stores BYTE OFFSETS into hq (src * 128) for address-free gather loads
__global__ __launch_bounds__(256) void k_csr(const unsigned int* __restrict__ ebuf,
                                             const int* __restrict__ hoff,
                                             int* __restrict__ rowptr, int* __restrict__ colidx) {
  __shared__ int lcnt[1024];
  __shared__ int lcur[1024];
  __shared__ int ssum[256];
  int b = blockIdx.x, tid = threadIdx.x;
  int ebeg = hoff[b * NBLK];
  int eend = (b + 1 < NBUK) ? hoff[(b + 1) * NBLK] : N_EDGESC;
  for (int i = tid; i < 1024; i += 256) lcnt[i] = 0;
  __syncthreads();
  for (int e = ebeg + tid; e < eend; e += 256) atomicAdd(&lcnt[ebuf[e] >> 17], 1);
  __syncthreads();
  int c0 = lcnt[tid * 4 + 0], c1 = lcnt[tid * 4 + 1], c2 = lcnt[tid * 4 + 2], c3 = lcnt[tid * 4 + 3];
  int s = c0 + c1 + c2 + c3;
  ssum[tid] = s;
  __syncthreads();
  for (int off = 1; off < 256; off <<= 1) {
    int t = (tid >= off) ? ssum[tid - off] : 0;
    __syncthreads();
    ssum[tid] += t;
    __syncthreads();
  }
  int excl = ssum[tid] - s;
  int node0 = (b << 10) + tid * 4;
  int ex = excl;
  lcur[tid * 4 + 0] = ex; if (node0 + 0 < N_NODESC) rowptr[node0 + 0] = ebeg + ex; ex += c0;
  lcur[tid * 4 + 1] = ex; if (node0 + 1 < N_NODESC) rowptr[node0 + 1] = ebeg + ex; ex += c1;
  lcur[tid * 4 + 2] = ex; if (node0 + 2 < N_NODESC) rowptr[node0 + 2] = ebeg + ex; ex += c2;
  lcur[tid * 4 + 3] = ex; if (node0 + 3 < N_NODESC) rowptr[node0 + 3] = ebeg + ex;
  __syncthreads();
  for (int e = ebeg + tid; e < eend; e += 256) {
    unsigned int u = ebuf[e];
    int pos = atomicAdd(&lcur[u >> 17], 1);
    colidx[ebeg + pos] = (int)((u & 0x1FFFFu) << 7);  // byte offset: src * HIDC
  }
  if (b == 0 && tid == 0) rowptr[N_NODESC] = N_EDGESC;
}

// agg over in-edges from fp8 shadow; one wave per node; bf16 agg output.
// lane = (edge slot g 0..3) x (8-col chunk l 0..15); uint2 = 8B fp8 per lane.
// colidx preloaded per <=64-edge window, broadcast via __shfl (wave-uniform only —
// ds_bpermute from an exec-masked lane returns garbage).
__global__ __launch_bounds__(256) void k_gather_q(const unsigned char* __restrict__ hq,
                                                  const int* __restrict__ rowptr,
                                                  const int* __restrict__ colidx,
                                                  unsigned short* __restrict__ aggb) {
  int node = blockIdx.x * 4 + (threadIdx.x >> 6);
  int lane = threadIdx.x & 63;
  if (node >= N_NODESC) return;
  int g = lane >> 4;   // edge slot 0..3
  int l = lane & 15;   // 8B chunk 0..15
  int beg = rowptr[node], end = rowptr[node + 1];
  f32x2 acc2[4];
#pragma unroll
  for (int i = 0; i < 4; ++i) acc2[i] = (f32x2){0.f, 0.f};
  int wbase = beg;
  int cv = (wbase + lane < end) ? colidx[wbase + lane] : 0;
  int e = beg;
  for (; e + 16 <= end; e += 16) {   // all conditions wave-uniform
    if (e + 16 > wbase + 64) {
      wbase = e;
      cv = (wbase + lane < end) ? colidx[wbase + lane] : 0;
    }
    int i0 = e - wbase;
    int o0 = __shfl(cv, i0 + g);
    int o1 = __shfl(cv, i0 + 4 + g);
    int o2 = __shfl(cv, i0 + 8 + g);
    int o3 = __shfl(cv, i0 + 12 + g);
    uint2 u0 = ((const uint2*)(hq + (size_t)(unsigned)o0))[l];
    uint2 u1 = ((const uint2*)(hq + (size_t)(unsigned)o1))[l];
    uint2 u2 = ((const uint2*)(hq + (size_t)(unsigned)o2))[l];
    uint2 u3 = ((const uint2*)(hq + (size_t)(unsigned)o3))[l];
    acc2[0] += __builtin_amdgcn_cvt_pk_f32_fp8((int)u0.x, false);
    acc2[1] += __builtin_amdgcn_cvt_pk_f32_fp8((int)u0.x, true);
    acc2[2] += __builtin_amdgcn_cvt_pk_f32_fp8((int)u0.y, false);
    acc2[3] += __builtin_amdgcn_cvt_pk_f32_fp8((int)u0.y, true);
    acc2[0] += __builtin_amdgcn_cvt_pk_f32_fp8((int)u1.x, false);
    acc2[1] += __builtin_amdgcn_cvt_pk_f32_fp8((int)u1.x, true);
    acc2[2] += __builtin_amdgcn_cvt_pk_f32_fp8((int)u1.y, false);
    acc2[3] += __builtin_amdgcn_cvt_pk_f32_fp8((int)u1.y, true);
    acc2[0] += __builtin_amdgcn_cvt_pk_f32_fp8((int)u2.x, false);
    acc2[1] += __builtin_amdgcn_cvt_pk_f32_fp8((int)u2.x, true);
    acc2[2] += __builtin_amdgcn_cvt_pk_f32_fp8((int)u2.y, false);
    acc2[3] += __builtin_amdgcn_cvt_pk_f32_fp8((int)u2.y, true);
    acc2[0] += __builtin_amdgcn_cvt_pk_f32_fp8((int)u3.x, false);
    acc2[1] += __builtin_amdgcn_cvt_pk_f32_fp8((int)u3.x, true);
    acc2[2] += __builtin_amdgcn_cvt_pk_f32_fp8((int)u3.y, false);
    acc2[3] += __builtin_amdgcn_cvt_pk_f32_fp8((int)u3.y, true);
  }
  if (e + 8 <= end) {                // wave-uniform
    if (e + 8 > wbase + 64) {
      wbase = e;
      cv = (wbase + lane < end) ? colidx[wbase + lane] : 0;
    }
    int i0 = e - wbase;
    int o0 = __shfl(cv, i0 + g);
    int o1 = __shfl(cv, i0 + 4 + g);
    uint2 u0 = ((const uint2*)(hq + (size_t)(unsigned)o0))[l];
    uint2 u1 = ((const uint2*)(hq + (size_t)(unsigned)o1))[l];
    acc2[0] += __builtin_amdgcn_cvt_pk_f32_fp8((int)u0.x, false);
    acc2[1] += __builtin_amdgcn_cvt_pk_f32_fp8((int)u0.x, true);
    acc2[2] += __builtin_amdgcn_cvt_pk_f32_fp8((int)u0.y, false);
    acc2[3] += __builtin_amdgcn_cvt_pk_f32_fp8((int)u0.y, true);
    acc2[0] += __builtin_amdgcn_cvt_pk_f32_fp8((int)u1.x, false);
    acc2[1] += __builtin_amdgcn_cvt_pk_f32_fp8((int)u1.x, true);
    acc2[2] += __builtin_amdgcn_cvt_pk_f32_fp8((int)u1.y, false);
    acc2[3] += __builtin_amdgcn_cvt_pk_f32_fp8((int)u1.y, true);
    e += 8;
  }
  // tail (up to 7 edges): shfl hoisted OUT of the divergent guard
  if (e < end) {                     // wave-uniform
    if (e + 8 > wbase + 64) {
      wbase = e;
      cv = (wbase + lane < end) ? colidx[wbase + lane] : 0;
    }
#pragma unroll
    for (int t = 0; t < 2; ++t) {
      int eg = e + t * 4 + g;
      int o0 = __shfl(cv, (eg - wbase) & 63);  // executed by ALL lanes
      if (eg < end) {                          // divergence only on load+acc
        uint2 u0 = ((const uint2*)(hq + (size_t)(unsigned)o0))[l];
        acc2[0] += __builtin_amdgcn_cvt_pk_f32_fp8((int)u0.x, false);
        acc2[1] += __builtin_amdgcn_cvt_pk_f32_fp8((int)u0.x, true);
        acc2[2] += __builtin_amdgcn_cvt_pk_f32_fp8((int)u0.y, false);
        acc2[3] += __builtin_amdgcn_cvt_pk_f32_fp8((int)u0.y, true);
      }
    }
  }
  // reduce across the 4 edge slots
#pragma unroll
  for (int i = 0; i < 4; ++i) {
    acc2[i].x += __shfl_xor(acc2[i].x, 16);
    acc2[i].y += __shfl_xor(acc2[i].y, 16);
    acc2[i].x += __shfl_xor(acc2[i].x, 32);
    acc2[i].y += __shfl_xor(acc2[i].y, 32);
  }
  if (g == 0) {
    uint4 o;
    o.x = (unsigned)f2bf(acc2[0].x) | ((unsigned)f2bf(acc2[0].y) << 16);
    o.y = (unsigned)f2bf(acc2[1].x) | ((unsigned)f2bf(acc2[1].y) << 16);
    o.z = (unsigned)f2bf(acc2[2].x) | ((unsigned)f2bf(acc2[2].y) << 16);
    o.w = (unsigned)f2bf(acc2[3].x) | ((unsigned)f2bf(acc2[3].y) << 16);
    ((uint4*)(aggb + (size_t)node * HIDC))[l] = o;
  }
}

// conv = [hb|aggb] @ M^T via MFMA bf16 (K=256); hb = bf16(hb + eps*tanh(conv+b)) in place;
// refresh fp8 shadow hq (skipped on last iteration). LDS holds ONLY the hb half (16 KB,
// swizzled); agg A-frags load directly from global (L2-hot). Epilogue in-place in LDS
// (wave-private rows, no barrier), then vectorized uint4/uint2 copy-out.
__global__ __launch_bounds__(256) void k_update_mfma(unsigned short* __restrict__ hb,
                                                     unsigned char* __restrict__ hq,
                                                     const unsigned short* __restrict__ aggb,
                                                     const unsigned short* __restrict__ MTP,
                                                     const float* __restrict__ asym_b,
                                                     int write_hq) {
  __shared__ __align__(16) unsigned char Als[64 * 256];  // 64 rows x 128 bf16 (hb), swizzled
  int tid = threadIdx.x;
  int r0 = blockIdx.x * 64;
  for (int i = tid; i < 1024; i += 256) {
    int row = i >> 4;
    int ck = i & 15;
    int gr = r0 + row;
    uint4 v = make_uint4(0u, 0u, 0u, 0u);
    if (gr < N_NODESC) v = ((const uint4*)(hb + (size_t)gr * HIDC))[ck];
    *(uint4*)(Als + row * 256 + ((ck * 16) ^ ((row & 7) << 4))) = v;
  }
  __syncthreads();
  int lane = tid & 63, w = tid >> 6;
  int m = lane & 15, g = lane >> 4;
  int arow = w * 16 + m;
  int garow = r0 + arow;
  if (garow >= N_NODESC) garow = N_NODESC - 1;  // clamp (pad-row results discarded)
  bf16x8 a[8];
#pragma unroll
  for (int kc = 0; kc < 4; ++kc) {
    a[kc] = *(const bf16x8*)(Als + arow * 256 + ((kc * 64 + g * 16) ^ ((arow & 7) << 4)));
  }
#pragma unroll
  for (int kc = 4; kc < 8; ++kc) {
    a[kc] = *(const bf16x8*)(aggb + (size_t)garow * HIDC + (kc - 4) * 32 + g * 8);
  }
  f32x4 acc[8];
#pragma unroll
  for (int ct = 0; ct < 8; ++ct) acc[ct] = (f32x4){0.f, 0.f, 0.f, 0.f};
#pragma unroll
  for (int ct = 0; ct < 8; ++ct) {
#pragma unroll
    for (int kc = 0; kc < 8; ++kc) {
      bf16x8 b = *(const bf16x8*)(MTP + ((size_t)((ct * 8 + kc) * 64 + lane)) * 8);
      acc[ct] = __builtin_amdgcn_mfma_f32_16x16x32_bf16(a[kc], b, acc[ct], 0, 0, 0);
    }
  }
  // epilogue: read h_old from LDS slot, write result back to the SAME slot (wave-private)
#pragma unroll
  for (int ct = 0; ct < 8; ++ct) {
    int col = ct * 16 + m;
    float bias = asym_b[col];
    int lb = col * 2;  // byte offset of col within a 256B row
#pragma unroll
    for (int j = 0; j < 4; ++j) {
      int lrow = w * 16 + g * 4 + j;
      int haddr = lrow * 256 + (((lb & ~15) ^ ((lrow & 7) << 4)) | (lb & 15));
      unsigned short hu = *(const unsigned short*)(Als + haddr);
      float hold = __uint_as_float((unsigned)hu << 16);
      float val = hold + EPSC * tanh_fast(acc[ct][j] + bias);
      *(unsigned short*)(Als + haddr) = f2bf(val);
    }
  }
  // copy-out: wave w copies its 16 rows; uint4 hb stores (+ uint2 hq stores unless last iter)
#pragma unroll
  for (int k = 0; k < 4; ++k) {
    int idx = k * 64 + lane;           // 0..255 per wave
    int row = w * 16 + (idx >> 4);
    int ck = idx & 15;                 // 16B chunk
    int gr = r0 + row;
    if (gr < N_NODESC) {
      uint4 v = *(const uint4*)(Als + row * 256 + ((ck * 16) ^ ((row & 7) << 4)));
      ((uint4*)(hb + (size_t)gr * HIDC))[ck] = v;
      if (write_hq) {
        float f0 = __uint_as_float(v.x << 16), f1 = __uint_as_float(v.x & 0xffff0000u);
        float f2 = __uint_as_float(v.y << 16), f3 = __uint_as_float(v.y & 0xffff0000u);
        float f4 = __uint_as_float(v.z << 16), f5 = __uint_as_float(v.z & 0xffff0000u);
        float f6 = __uint_as_float(v.w << 16), f7 = __uint_as_float(v.w & 0xffff0000u);
        unsigned int w0 = 0u, w1 = 0u;
        w0 = (unsigned int)__builtin_amdgcn_cvt_pk_fp8_f32(f0, f1, (int)w0, false);
        w0 = (unsigned int)__builtin_amdgcn_cvt_pk_fp8_f32(f2, f3, (int)w0, true);
        w1 = (unsigned int)__builtin_amdgcn_cvt_pk_fp8_f32(f4, f5, (int)w1, false);
        w1 = (unsigned int)__builtin_amdgcn_cvt_pk_fp8_f32(f6, f7, (int)w1, true);
        uint2 q;
        q.x = w0;
        q.y = w1;
        ((uint2*)(hq + (size_t)gr * HIDC))[ck] = q;
      }
    }
  }
}

__device__ __forceinline__ int lbound_batch(const int* __restrict__ a, int key) {
  int lo = 0, hi = N_NODESC;
  while (lo < hi) {
    int mid = (lo + hi) >> 1;
    if (a[mid] < key) lo = mid + 1;
    else hi = mid;
  }
  return lo;
}

__global__ __launch_bounds__(128) void k_pool1(const unsigned short* __restrict__ hb,
                                               const int* __restrict__ batch,
                                               float* __restrict__ part) {
  int g = blockIdx.x / POOL_CHUNKS;
  int j = blockIdx.x % POOL_CHUNKS;
  int c = threadIdx.x;
  int lo = lbound_batch(batch, g);
  int hi = lbound_batch(batch, g + 1);
  int n = hi - lo;
  int ch = (n + POOL_CHUNKS - 1) / POOL_CHUNKS;
  int b = lo + j * ch;
  int e = b + ch;
  if (e > hi) e = hi;
  float s = 0.f, m = -INFINITY;
  for (int i = b; i < e; ++i) {
    unsigned short u = hb[(size_t)i * HIDC + c];
    float v = __uint_as_float((unsigned)u << 16);
    s += v;
    m = fmaxf(m, v);
  }
  size_t o = ((size_t)g * POOL_CHUNKS + j) * 256;
  part[o + c] = s;
  part[o + 128 + c] = m;
}

// fused: combine pool partials -> [add|max|mean] -> mlp1 -> mlp2 -> out. one block per graph.
__global__ __launch_bounds__(192) void k_tail(const float* __restrict__ part,
                                              const int* __restrict__ batch,
                                              const float* __restrict__ r1_w,
                                              const float* __restrict__ r1_b,
                                              const float* __restrict__ r2_w,
                                              const float* __restrict__ r2_b,
                                              float* __restrict__ out) {
  __shared__ float gv[384];
  __shared__ float g1[192];
  int g = blockIdx.x;
  int tid = threadIdx.x;
  if (tid < 128) {
    int c = tid;
    float s = 0.f, m = -INFINITY;
#pragma unroll
    for (int j = 0; j < POOL_CHUNKS; ++j) {
      size_t o = ((size_t)g * POOL_CHUNKS + j) * 256;
      s += part[o + c];
      m = fmaxf(m, part[o + 128 + c]);
    }
    int lo = lbound_batch(batch, g);
    int hi = lbound_batch(batch, g + 1);
    float cntf = (float)(hi - lo);
    gv[c] = s;
    gv[128 + c] = m;
    gv[256 + c] = s / fmaxf(cntf, 1.f);
  }
  __syncthreads();
  {
    int j = tid;
    float acc = r1_b[j];
    const float* wr = r1_w + (size_t)j * 384;
#pragma unroll 4
    for (int k = 0; k < 384; ++k) acc = fmaf(gv[k], wr[k], acc);
    g1[j] = (acc > 0.f) ? acc : 0.01f * acc;
  }
  __syncthreads();
  if (tid < OUT_DIMC) {
    int o = tid;
    float acc = r2_b[o];
    const float* wr = r2_w + o * 192;
    for (int k = 0; k < 192; ++k) acc = fmaf(g1[k], wr[k], acc);
    out[g * OUT_DIMC + o] = (acc > 0.f) ? acc : 0.01f * acc;
  }
}

extern "C" void kernel_launch(void* const* d_in, const int* in_sizes, int n_in,
                              void* d_out, int out_size, void* d_ws, size_t ws_size,
                              hipStream_t stream) {
  const float* x      = (const float*)d_in[0];
  const int*   ei     = (const int*)d_in[1];
  const int*   batch  = (const int*)d_in[2];
  const float* emb_w  = (const float*)d_in[3];
  const float* emb_b  = (const float*)d_in[4];
  const float* W      = (const float*)d_in[5];
  const float* asym_b = (const float*)d_in[6];
  const float* lin_w  = (const float*)d_in[7];
  const float* r1_w   = (const float*)d_in[8];
  const float* r1_b   = (const float*)d_in[9];
  const float* r2_w   = (const float*)d_in[10];
  const float* r2_b   = (const float*)d_in[11];
  float* out = (float*)d_out;

  char* ws = (char*)d_ws;
  size_t off = 0;
  auto alloc = [&](size_t bytes) -> char* {
    char* p = ws + off;
    off += (bytes + 255) & ~(size_t)255;
    return p;
  };
  unsigned short* hb  = (unsigned short*)alloc((size_t)N_NODESC * HIDC * 2);  // 25.6 MB
  unsigned char*  hq  = (unsigned char*)alloc((size_t)N_NODESC * HIDC);       // 12.8 MB
  unsigned short* ab  = (unsigned short*)alloc((size_t)N_NODESC * HIDC * 2);  // 25.6 MB
  unsigned short* MTP = (unsigned short*)alloc((size_t)32768 * 2);            // 64 KB
  unsigned short* EWP = (unsigned short*)alloc((size_t)8192 * 2);             // 16 KB
  int* rowptr   = (int*)alloc((size_t)(N_NODESC + 1) * 4);
  int* colidx   = (int*)alloc((size_t)(N_EDGESC + 64) * 4);         // 6.4 MB (+pad)
  unsigned int* ebuf = (unsigned int*)alloc((size_t)N_EDGESC * 4);  // 6.4 MB
  int* histg    = (int*)alloc((size_t)NHIST * 4);
  int* hoff     = (int*)alloc((size_t)NHIST * 4);
  int* bsum     = (int*)alloc((size_t)S1NB * 4);
  int* boff     = (int*)alloc((size_t)S1NB * 4);
  float* part   = (float*)alloc((size_t)N_GRAPHSC * POOL_CHUNKS * 256 * 4);
  (void)ws_size; (void)in_sizes; (void)n_in; (void)out_size;

  const int* srcv = ei;
  const int* dstv = ei + N_EDGESC;

  k_pack<<<(32768 + 8192 + 255) / 256, 256, 0, stream>>>(W, lin_w, emb_w, MTP, EWP);
  k_embed_mfma<<<UPD_NB, 256, 0, stream>>>(x, EWP, emb_b, hb, hq);
  k_hist<<<NBLK, 256, 0, stream>>>(dstv, histg);
  k_s1<<<S1NB, 256, 0, stream>>>(histg, bsum);
  k_s2<<<1, 256, 0, stream>>>(bsum, boff);
  k_s3<<<S1NB, 256, 0, stream>>>(histg, boff, hoff);
  k_scatter<<<NBLK, 256, 0, stream>>>(srcv, dstv, hoff, ebuf);
  k_csr<<<NBUK, 256, 0, stream>>>(ebuf, hoff, rowptr, colidx);
  for (int it = 0; it < NUM_ITERSC; ++it) {
    k_gather_q<<<N_NODESC / 4, 256, 0, stream>>>(hq, rowptr, colidx, ab);
    k_update_mfma<<<UPD_NB, 256, 0, stream>>>(hb, hq, ab, MTP, asym_b,
                                              (it < NUM_ITERSC - 1) ? 1 : 0);
  }
  k_pool1<<<N_GRAPHSC * POOL_CHUNKS, 128, 0, stream>>>(hb, batch, part);
  k_tail<<<N_GRAPHSC, 192, 0, stream>>>(part, batch, r1_w, r1_b, r2_w, r2_b, out);
}